// Round 8
// baseline (450.027 us; speedup 1.0000x reference)
//
#include <hip/hip_runtime.h>
#include <hip/hip_bf16.h>
#include <cstdint>
#include <cstddef>

#define NN 65536
#define NE 262144
#define NB 2048
#define FIN 78
#define GOUTD 512

typedef __bf16 bf16x8 __attribute__((ext_vector_type(8)));
typedef float f32x4 __attribute__((ext_vector_type(4)));

__device__ __forceinline__ float leaky02(float x) { return x > 0.f ? x : 0.2f * x; }
__device__ __forceinline__ void atomAddF(float* p, float v) { unsafeAtomicAdd(p, v); }

// ---------------- CSR build ----------------
__global__ void k_hist(const int* __restrict__ dst, int* __restrict__ deg) {
    int i = blockIdx.x * 256 + threadIdx.x;
    if (i < NE) atomicAdd(&deg[dst[i]], 1);
}

__global__ void k_scan_block(const int* __restrict__ deg, int* __restrict__ ex, int* __restrict__ bsum) {
    __shared__ int s[256];
    int t = threadIdx.x; int g = blockIdx.x * 256 + t;
    int v = deg[g];
    s[t] = v; __syncthreads();
    for (int d = 1; d < 256; d <<= 1) {
        int x = (t >= d) ? s[t - d] : 0;
        __syncthreads();
        s[t] += x;
        __syncthreads();
    }
    ex[g] = s[t] - v;
    if (t == 255) bsum[blockIdx.x] = s[t];
}

// merged scan_bsum + scan_add
__global__ void k_scan_add2(int* __restrict__ rowptr, const int* __restrict__ bsum) {
    __shared__ int s[256];
    int t = threadIdx.x;
    int v = bsum[t];
    s[t] = v; __syncthreads();
    for (int d = 1; d < 256; d <<= 1) {
        int x = (t >= d) ? s[t - d] : 0;
        __syncthreads();
        s[t] += x;
        __syncthreads();
    }
    int prefix = (blockIdx.x == 0) ? 0 : s[blockIdx.x - 1];
    int i = blockIdx.x * 256 + t;
    rowptr[i] += prefix;
    if (i == 0) rowptr[NN] = NE;
}

__global__ void k_scatter(const int* __restrict__ src, const int* __restrict__ dst,
                          const int* __restrict__ rowptr, int* __restrict__ fill,
                          int* __restrict__ colI) {
    int i = blockIdx.x * 256 + threadIdx.x;
    if (i < NE) {
        int d = dst[i];
        int pos = rowptr[d] + atomicAdd(&fill[d], 1);
        colI[pos] = src[i];
    }
}

// ---------------- merged conversions + prep: x->xb, W1^T, W2^T, deg/fill zero, gstart ----------------
__global__ void k_cvt_prep(const float* __restrict__ x, const float* __restrict__ W1,
                           const float* __restrict__ W2, __hip_bfloat16* __restrict__ xb,
                           __hip_bfloat16* __restrict__ w1t, __hip_bfloat16* __restrict__ w2t,
                           int* __restrict__ deg, int* __restrict__ fill,
                           const int* __restrict__ batch, int* __restrict__ gstart)
{
    int blk = blockIdx.x;
    if (blk < 16384) {
        int i = blk * 256 + threadIdx.x;
        int row = i >> 6;
        int c = (i & 63) << 1;
        float v0 = (c < FIN) ? x[(size_t)row * FIN + c] : 0.f;
        float v1 = (c + 1 < FIN) ? x[(size_t)row * FIN + c + 1] : 0.f;
        __hip_bfloat16 o[2];
        o[0] = __float2bfloat16(v0);
        o[1] = __float2bfloat16(v1);
        *(uint32_t*)&xb[(size_t)row * 128 + c] = *(const uint32_t*)o;
    } else if (blk < 16640) {
        int i = (blk - 16384) * 256 + threadIdx.x;   // over 512*128
        int n = i >> 7, k = i & 127;
        w1t[i] = __float2bfloat16(k < FIN ? W1[(size_t)k * 512 + n] : 0.f);
    } else if (blk < 17664) {
        int i = (blk - 16640) * 256 + threadIdx.x;   // over 512*512
        int n = i >> 9, k = i & 511;
        w2t[i] = __float2bfloat16(W2[(size_t)k * 512 + n]);
    } else {
        int i = (blk - 17664) * 256 + threadIdx.x;   // prep over NN
        if (i < NN) {
            deg[i] = 0; fill[i] = 0;
            int cur = batch[i];
            int prev = (i == 0) ? -1 : batch[i - 1];
            for (int g = prev + 1; g <= cur; ++g) gstart[g] = i;
            if (i == NN - 1) {
                for (int g = cur + 1; g <= NB; ++g) gstart[g] = NN;
            }
        }
    }
}

// ---------------- bf16 MFMA GEMM + fused attention logits ----------------
// Tail (2nd call only, gated by t1!=nullptr): init t1 rows = fb1, t2 rows = fb2,
// zero z1 rows (for atomic-accumulate geno1 GEMM).
__global__ __launch_bounds__(256) void k_mfma_gemm(
    const __hip_bfloat16* __restrict__ A, const __hip_bfloat16* __restrict__ BT,
    __hip_bfloat16* __restrict__ C, int K,
    const float* __restrict__ att_src, const float* __restrict__ att_dst,
    float* __restrict__ a_src, float* __restrict__ a_dst,
    float* __restrict__ t1, float* __restrict__ t2,
    const float* __restrict__ fb1, const float* __restrict__ fb2,
    float* __restrict__ z1)
{
    __shared__ __hip_bfloat16 smem[128 * 128];          // 32 KB
    __hip_bfloat16* As = smem;
    __hip_bfloat16* Bs = smem + 128 * 64;
    int tid = threadIdx.x;
    int lane = tid & 63;
    int wave = tid >> 6;
    int id = blockIdx.x;
    int m0 = (((id >> 5) << 3) + (id & 7)) * 128;
    int n0 = ((id >> 3) & 3) * 128;
    int wm = (wave >> 1) * 64;
    int wn = (wave & 1) * 64;
    f32x4 acc[4][4] = {};

    int swz = lane & 7;

    for (int k0 = 0; k0 < K; k0 += 64) {
        #pragma unroll
        for (int c = 0; c < 4; ++c) {
            int off = c * 4096 + tid * 16;
            int r = off >> 7;
            int c16 = (off >> 4) & 7;
            int c16s = c16 ^ (r & 7);
            __builtin_amdgcn_global_load_lds(
                (const __attribute__((address_space(1))) void*)(A + (size_t)(m0 + r) * K + k0 + c16s * 8),
                (__attribute__((address_space(3))) void*)((char*)As + off), 16, 0, 0);
            __builtin_amdgcn_global_load_lds(
                (const __attribute__((address_space(1))) void*)(BT + (size_t)(n0 + r) * K + k0 + c16s * 8),
                (__attribute__((address_space(3))) void*)((char*)Bs + off), 16, 0, 0);
        }
        __syncthreads();
        #pragma unroll
        for (int kk = 0; kk < 64; kk += 32) {
            int c16r = (kk >> 3) + (lane >> 4);
            bf16x8 af[4], bfr[4];
            #pragma unroll
            for (int t = 0; t < 4; ++t) {
                int ra = wm + t * 16 + (lane & 15);
                int rb = wn + t * 16 + (lane & 15);
                af[t]  = *(const bf16x8*)((char*)As + ra * 128 + ((c16r ^ swz) << 4));
                bfr[t] = *(const bf16x8*)((char*)Bs + rb * 128 + ((c16r ^ swz) << 4));
            }
            #pragma unroll
            for (int i = 0; i < 4; ++i)
                #pragma unroll
                for (int j = 0; j < 4; ++j)
                    acc[i][j] = __builtin_amdgcn_mfma_f32_16x16x32_bf16(af[i], bfr[j], acc[i][j], 0, 0, 0);
        }
        __syncthreads();
    }

    // ---- epilogue: acc -> LDS (bank-swizzled) -> coalesced stores + fused attn dots ----
    int rowb = wm + ((lane >> 4) << 2);
    int colb = wn + (lane & 15);
    #pragma unroll
    for (int i = 0; i < 4; ++i) {
        #pragma unroll
        for (int j = 0; j < 4; ++j) {
            int cc = colb + j * 16;
            #pragma unroll
            for (int r = 0; r < 4; ++r) {
                int rr = rowb + i * 16 + r;
                int word = (cc >> 1) ^ (((rr >> 2) & 7) << 3);
                smem[rr * 128 + word * 2 + (cc & 1)] = __float2bfloat16(acc[i][j][r]);
            }
        }
    }
    __syncthreads();
    #pragma unroll
    for (int cc2 = 0; cc2 < 8; ++cc2) {
        int p = cc2 * 256 + tid;
        int rr = p >> 4;          // tile row 0..127
        int c16 = p & 15;         // 16B chunk (= 8 cols) within 128-col row
        int x = ((rr >> 2) & 7) << 3;
        bf16x8 v = *(const bf16x8*)((char*)smem + rr * 256 + ((((c16 << 2) ^ x)) << 2));
        *(bf16x8*)(C + (size_t)(m0 + rr) * 512 + n0 + c16 * 8) = v;
        // fused attention logits: chunks 0..7 = head (n0>>6), 8..15 = head+1
        const float* sp = att_src + n0 + c16 * 8;
        const float* dp = att_dst + n0 + c16 * 8;
        float4 s0 = *(const float4*)sp, s1 = *(const float4*)(sp + 4);
        float4 d0 = *(const float4*)dp, d1 = *(const float4*)(dp + 4);
        float sv[8] = {s0.x, s0.y, s0.z, s0.w, s1.x, s1.y, s1.z, s1.w};
        float dv[8] = {d0.x, d0.y, d0.z, d0.w, d1.x, d1.y, d1.z, d1.w};
        float ps = 0.f, pd = 0.f;
        #pragma unroll
        for (int k = 0; k < 8; ++k) {
            float f = (float)v[k];
            ps = fmaf(f, sv[k], ps);
            pd = fmaf(f, dv[k], pd);
        }
        #pragma unroll
        for (int d = 1; d < 8; d <<= 1) {
            ps += __shfl_xor(ps, d);
            pd += __shfl_xor(pd, d);
        }
        if ((c16 & 7) == 0) {
            int head = (n0 >> 6) + (c16 >> 3);
            a_src[(size_t)(m0 + rr) * 8 + head] = ps;
            a_dst[(size_t)(m0 + rr) * 8 + head] = pd;
        }
    }

    // ---- tail (layer-2 call only): init t1/t2 rows to bias, zero z1 row ----
    if (t1) {
        if (tid < 64)  *(float4*)(t1 + (size_t)id * 256 + tid * 4) = *(const float4*)(fb1 + tid * 4);
        if (tid < 32)  *(float4*)(t2 + (size_t)id * 128 + tid * 4) = *(const float4*)(fb2 + tid * 4);
        if (tid >= 64 && tid < 96)
            *(float4*)(z1 + (size_t)id * 128 + (tid - 64) * 4) = make_float4(0.f, 0.f, 0.f, 0.f);
    }
}

// ---------------- GAT aggregate (layer 1): 4-wide edge pipeline ----------------
// 4 colI (sequential), 4 asrc gathers, 4 independent 1KB h-gathers all issued
// before the FMA block (h-gather depends only on colI, not asrc). avg deg=4 ->
// main body runs ~once/node, tail is the verified 2+1 code.
__global__ __launch_bounds__(256) void k_gat_agg(
    const __hip_bfloat16* __restrict__ h, const float* __restrict__ asrc,
    const float* __restrict__ adst, const int* __restrict__ rowptr,
    const int* __restrict__ colI, const float* __restrict__ bias,
    __hip_bfloat16* __restrict__ out)
{
    int lane = threadIdx.x & 63;
    int n = blockIdx.x * 4 + (threadIdx.x >> 6);
    int start = rowptr[n], end = rowptr[n + 1];
    int hh = lane >> 3;
    float adst_h = adst[n * 8 + hh];
    float acc[8];
    float wsum;
    {
        float w = __expf(leaky02(asrc[n * 8 + hh] + adst_h));   // self loop
        wsum = w;
        bf16x8 v = *(const bf16x8*)(h + (size_t)n * GOUTD + lane * 8);
        #pragma unroll
        for (int j = 0; j < 8; ++j) acc[j] = w * (float)v[j];
    }
    int i = start;
    for (; i + 3 < end; i += 4) {
        int s0 = colI[i], s1 = colI[i + 1], s2 = colI[i + 2], s3 = colI[i + 3];
        float w0 = __expf(leaky02(asrc[s0 * 8 + hh] + adst_h));
        float w1 = __expf(leaky02(asrc[s1 * 8 + hh] + adst_h));
        float w2 = __expf(leaky02(asrc[s2 * 8 + hh] + adst_h));
        float w3 = __expf(leaky02(asrc[s3 * 8 + hh] + adst_h));
        bf16x8 v0 = *(const bf16x8*)(h + (size_t)s0 * GOUTD + lane * 8);
        bf16x8 v1 = *(const bf16x8*)(h + (size_t)s1 * GOUTD + lane * 8);
        bf16x8 v2 = *(const bf16x8*)(h + (size_t)s2 * GOUTD + lane * 8);
        bf16x8 v3 = *(const bf16x8*)(h + (size_t)s3 * GOUTD + lane * 8);
        wsum += (w0 + w1) + (w2 + w3);
        #pragma unroll
        for (int j = 0; j < 8; ++j)
            acc[j] = fmaf(w3, (float)v3[j], fmaf(w2, (float)v2[j],
                     fmaf(w1, (float)v1[j], fmaf(w0, (float)v0[j], acc[j]))));
    }
    for (; i + 1 < end; i += 2) {
        int s0 = colI[i];
        int s1 = colI[i + 1];
        float w0 = __expf(leaky02(asrc[s0 * 8 + hh] + adst_h));
        float w1 = __expf(leaky02(asrc[s1 * 8 + hh] + adst_h));
        bf16x8 v0 = *(const bf16x8*)(h + (size_t)s0 * GOUTD + lane * 8);
        bf16x8 v1 = *(const bf16x8*)(h + (size_t)s1 * GOUTD + lane * 8);
        wsum += w0 + w1;
        #pragma unroll
        for (int j = 0; j < 8; ++j)
            acc[j] = fmaf(w0, (float)v0[j], fmaf(w1, (float)v1[j], acc[j]));
    }
    if (i < end) {
        int s = colI[i];
        float w = __expf(leaky02(asrc[s * 8 + hh] + adst_h));
        wsum += w;
        bf16x8 v = *(const bf16x8*)(h + (size_t)s * GOUTD + lane * 8);
        #pragma unroll
        for (int j = 0; j < 8; ++j) acc[j] = fmaf(w, (float)v[j], acc[j]);
    }
    float rden = 1.f / (wsum + 1e-16f);
    const float* bp = bias + lane * 8;
    float4 b0 = *(const float4*)bp, b1 = *(const float4*)(bp + 4);
    float bb[8] = {b0.x, b0.y, b0.z, b0.w, b1.x, b1.y, b1.z, b1.w};
    __hip_bfloat16 o[8] __attribute__((aligned(16)));
    #pragma unroll
    for (int j = 0; j < 8; ++j) {
        float v = fmaf(acc[j], rden, bb[j]);
        v = (v > 0.f) ? v : (__expf(v) - 1.f);
        o[j] = __float2bfloat16(v);
    }
    *(bf16x8*)(out + (size_t)n * GOUTD + lane * 8) = *(const bf16x8*)o;
}

// ---------------- GAT aggregate layer 2 + fused mean-pool: ONE BLOCK PER GRAPH ----------------
// 4-wide edge pipeline (same as k_gat_agg). R7 profile: aggpool ran at 2.9 TB/s vs
// agg1's 4.0 -- fewer waves (8192 vs 65536) so per-wave MLP matters more here.
__global__ __launch_bounds__(256) void k_gat_agg_pool(
    const __hip_bfloat16* __restrict__ h, const float* __restrict__ asrc,
    const float* __restrict__ adst, const int* __restrict__ rowptr,
    const int* __restrict__ colI, const float* __restrict__ bias,
    const int* __restrict__ gstart, float* __restrict__ cfeat)
{
    __shared__ float red[4][512];
    int lane = threadIdx.x & 63;
    int wv = threadIdx.x >> 6;
    int g = blockIdx.x;
    int s = gstart[g], e = gstart[g + 1];
    int hh = lane >> 3;
    const float* bp = bias + lane * 8;
    float4 b0 = *(const float4*)bp, b1 = *(const float4*)(bp + 4);
    float bb[8] = {b0.x, b0.y, b0.z, b0.w, b1.x, b1.y, b1.z, b1.w};
    float psum[8] = {};
    for (int n = s + wv; n < e; n += 4) {
        int start = rowptr[n], end = rowptr[n + 1];
        float adst_h = adst[n * 8 + hh];
        float acc[8];
        float wsum;
        {
            float w = __expf(leaky02(asrc[n * 8 + hh] + adst_h));   // self loop
            wsum = w;
            bf16x8 v = *(const bf16x8*)(h + (size_t)n * GOUTD + lane * 8);
            #pragma unroll
            for (int j = 0; j < 8; ++j) acc[j] = w * (float)v[j];
        }
        int i = start;
        for (; i + 3 < end; i += 4) {
            int s0 = colI[i], s1 = colI[i + 1], s2 = colI[i + 2], s3 = colI[i + 3];
            float w0 = __expf(leaky02(asrc[s0 * 8 + hh] + adst_h));
            float w1 = __expf(leaky02(asrc[s1 * 8 + hh] + adst_h));
            float w2 = __expf(leaky02(asrc[s2 * 8 + hh] + adst_h));
            float w3 = __expf(leaky02(asrc[s3 * 8 + hh] + adst_h));
            bf16x8 v0 = *(const bf16x8*)(h + (size_t)s0 * GOUTD + lane * 8);
            bf16x8 v1 = *(const bf16x8*)(h + (size_t)s1 * GOUTD + lane * 8);
            bf16x8 v2 = *(const bf16x8*)(h + (size_t)s2 * GOUTD + lane * 8);
            bf16x8 v3 = *(const bf16x8*)(h + (size_t)s3 * GOUTD + lane * 8);
            wsum += (w0 + w1) + (w2 + w3);
            #pragma unroll
            for (int j = 0; j < 8; ++j)
                acc[j] = fmaf(w3, (float)v3[j], fmaf(w2, (float)v2[j],
                         fmaf(w1, (float)v1[j], fmaf(w0, (float)v0[j], acc[j]))));
        }
        for (; i + 1 < end; i += 2) {
            int s0 = colI[i];
            int s1 = colI[i + 1];
            float w0 = __expf(leaky02(asrc[s0 * 8 + hh] + adst_h));
            float w1 = __expf(leaky02(asrc[s1 * 8 + hh] + adst_h));
            bf16x8 v0 = *(const bf16x8*)(h + (size_t)s0 * GOUTD + lane * 8);
            bf16x8 v1 = *(const bf16x8*)(h + (size_t)s1 * GOUTD + lane * 8);
            wsum += w0 + w1;
            #pragma unroll
            for (int j = 0; j < 8; ++j)
                acc[j] = fmaf(w0, (float)v0[j], fmaf(w1, (float)v1[j], acc[j]));
        }
        if (i < end) {
            int si = colI[i];
            float w = __expf(leaky02(asrc[si * 8 + hh] + adst_h));
            wsum += w;
            bf16x8 v = *(const bf16x8*)(h + (size_t)si * GOUTD + lane * 8);
            #pragma unroll
            for (int j = 0; j < 8; ++j) acc[j] = fmaf(w, (float)v[j], acc[j]);
        }
        float rden = 1.f / (wsum + 1e-16f);
        #pragma unroll
        for (int j = 0; j < 8; ++j) {
            float v = fmaf(acc[j], rden, bb[j]);
            v = (v > 0.f) ? v : (__expf(v) - 1.f);   // ELU
            psum[j] += v;
        }
    }
    #pragma unroll
    for (int j = 0; j < 8; ++j) red[wv][lane * 8 + j] = psum[j];
    __syncthreads();
    if (wv == 0) {
        float inv = 1.f / fmaxf((float)(e - s), 1.f);
        float* cp = cfeat + (size_t)g * 1024;
        #pragma unroll
        for (int j = 0; j < 8; ++j) {
            int c = lane * 8 + j;
            cp[c] = (red[0][c] + red[1][c] + red[2][c] + red[3][c]) * inv;
        }
    }
}

// ---------------- geno layer 1 as split-K GEMM: x_gen[2048,735] @ gW1[735,128] ----------------
__global__ __launch_bounds__(256) void k_geno1_sk(
    const float* __restrict__ A, const float* __restrict__ B, float* __restrict__ z1)
{
    __shared__ float As[32][34];
    __shared__ float Bs[32][68];
    int tid = threadIdx.x;
    int n0 = blockIdx.x * 64;            // 0 or 64 (N=128)
    int m0 = blockIdx.y * 32;
    int kbase = blockIdx.z * 192;
    int am = tid >> 3;
    int ak = (tid & 7) << 2;
    int bk = tid >> 4;
    int bc = (tid & 15) << 2;
    int tm = (tid >> 4) << 1;
    int tn = (tid & 15) << 2;
    float acc[2][4] = {};
    for (int kt = 0; kt < 192; kt += 32) {
        const float* ap = A + (size_t)(m0 + am) * 735 + kbase + kt + ak;
        int kg = kbase + kt + ak;
        As[ak][am]     = (kg     < 735) ? ap[0] : 0.f;
        As[ak + 1][am] = (kg + 1 < 735) ? ap[1] : 0.f;
        As[ak + 2][am] = (kg + 2 < 735) ? ap[2] : 0.f;
        As[ak + 3][am] = (kg + 3 < 735) ? ap[3] : 0.f;
        #pragma unroll
        for (int j = 0; j < 2; ++j) {
            int kr = j * 16 + bk;
            int kgb = kbase + kt + kr;
            float4 b4 = (kgb < 735) ? *(const float4*)(B + (size_t)kgb * 128 + n0 + bc)
                                    : make_float4(0.f, 0.f, 0.f, 0.f);
            *(float4*)&Bs[kr][bc] = b4;
        }
        __syncthreads();
        #pragma unroll
        for (int kk = 0; kk < 32; ++kk) {
            float2 a2 = *(const float2*)&As[kk][tm];
            float4 b4 = *(const float4*)&Bs[kk][tn];
            acc[0][0] = fmaf(a2.x, b4.x, acc[0][0]); acc[0][1] = fmaf(a2.x, b4.y, acc[0][1]);
            acc[0][2] = fmaf(a2.x, b4.z, acc[0][2]); acc[0][3] = fmaf(a2.x, b4.w, acc[0][3]);
            acc[1][0] = fmaf(a2.y, b4.x, acc[1][0]); acc[1][1] = fmaf(a2.y, b4.y, acc[1][1]);
            acc[1][2] = fmaf(a2.y, b4.z, acc[1][2]); acc[1][3] = fmaf(a2.y, b4.w, acc[1][3]);
        }
        __syncthreads();
    }
    #pragma unroll
    for (int i = 0; i < 2; ++i) {
        float* cp = z1 + (size_t)(m0 + tm + i) * 128 + n0 + tn;
        #pragma unroll
        for (int j = 0; j < 4; ++j) atomAddF(cp + j, acc[i][j]);
    }
}

// ---------------- geno layer 2 GEMM with fused BN+relu on A-load ----------------
__global__ __launch_bounds__(256) void k_geno2(
    const float* __restrict__ z1, const float* __restrict__ gW2,
    const float* __restrict__ gb1, const float* __restrict__ bn_mean,
    const float* __restrict__ bn_var, const float* __restrict__ bn_gamma,
    const float* __restrict__ bn_beta, const float* __restrict__ gb2,
    float* __restrict__ Cout)
{
    __shared__ float As[32][34];
    __shared__ float Bs[32][68];
    int tid = threadIdx.x;
    int n0 = blockIdx.x * 64;            // N=512 -> 8 n-blocks
    int m0 = blockIdx.y * 32;
    int am = tid >> 3;
    int ak = (tid & 7) << 2;
    int bk = tid >> 4;
    int bc = (tid & 15) << 2;
    int tm = (tid >> 4) << 1;
    int tn = (tid & 15) << 2;
    float acc[2][4] = {};
    for (int kt = 0; kt < 128; kt += 32) {
        int kg = kt + ak;
        float4 raw = *(const float4*)(z1 + (size_t)(m0 + am) * 128 + kg);
        float4 g1 = *(const float4*)(gb1 + kg);
        float4 mu = *(const float4*)(bn_mean + kg);
        float4 vr = *(const float4*)(bn_var + kg);
        float4 gm = *(const float4*)(bn_gamma + kg);
        float4 bt = *(const float4*)(bn_beta + kg);
        As[ak][am]     = fmaxf(fmaf(raw.x + g1.x - mu.x, rsqrtf(vr.x + 1e-5f) * gm.x, bt.x), 0.f);
        As[ak + 1][am] = fmaxf(fmaf(raw.y + g1.y - mu.y, rsqrtf(vr.y + 1e-5f) * gm.y, bt.y), 0.f);
        As[ak + 2][am] = fmaxf(fmaf(raw.z + g1.z - mu.z, rsqrtf(vr.z + 1e-5f) * gm.z, bt.z), 0.f);
        As[ak + 3][am] = fmaxf(fmaf(raw.w + g1.w - mu.w, rsqrtf(vr.w + 1e-5f) * gm.w, bt.w), 0.f);
        #pragma unroll
        for (int j = 0; j < 2; ++j) {
            int kr = j * 16 + bk;
            *(float4*)&Bs[kr][bc] = *(const float4*)(gW2 + (size_t)(kt + kr) * 512 + n0 + bc);
        }
        __syncthreads();
        #pragma unroll
        for (int kk = 0; kk < 32; ++kk) {
            float2 a2 = *(const float2*)&As[kk][tm];
            float4 b4 = *(const float4*)&Bs[kk][tn];
            acc[0][0] = fmaf(a2.x, b4.x, acc[0][0]); acc[0][1] = fmaf(a2.x, b4.y, acc[0][1]);
            acc[0][2] = fmaf(a2.x, b4.z, acc[0][2]); acc[0][3] = fmaf(a2.x, b4.w, acc[0][3]);
            acc[1][0] = fmaf(a2.y, b4.x, acc[1][0]); acc[1][1] = fmaf(a2.y, b4.y, acc[1][1]);
            acc[1][2] = fmaf(a2.y, b4.z, acc[1][2]); acc[1][3] = fmaf(a2.y, b4.w, acc[1][3]);
        }
        __syncthreads();
    }
    float4 bb = *(const float4*)(gb2 + n0 + tn);
    #pragma unroll
    for (int i = 0; i < 2; ++i) {
        float* cp = Cout + (size_t)(m0 + tm + i) * 1024 + n0 + tn;   // Cout pre-offset by 512
        *(float4*)cp = make_float4(fmaxf(acc[i][0] + bb.x, 0.f), fmaxf(acc[i][1] + bb.y, 0.f),
                                   fmaxf(acc[i][2] + bb.z, 0.f), fmaxf(acc[i][3] + bb.w, 0.f));
    }
}

// ---------------- fusion MLP layers 1-2: split-K fp32 GEMM, atomic accumulate ----------------
#define FBM 32
#define FBN 64
#define FKS 32

__global__ __launch_bounds__(256) void k_fgemm_sk(
    const float* __restrict__ A, const float* __restrict__ B,
    float* __restrict__ C, int N, int K, int KS, int reluA)
{
    __shared__ float As[FKS][FBM + 2];   // [k][m]
    __shared__ float Bs[FKS][FBN + 4];   // [k][n]
    int tid = threadIdx.x;
    int n0 = blockIdx.x * FBN;
    int m0 = blockIdx.y * FBM;
    int kbase = blockIdx.z * KS;
    int am = tid >> 3;
    int ak = (tid & 7) << 2;
    int bk = tid >> 4;
    int bc = (tid & 15) << 2;
    int tm = (tid >> 4) << 1;
    int tn = (tid & 15) << 2;
    float acc[2][4] = {};
    for (int kt = 0; kt < KS; kt += FKS) {
        float4 a4 = *(const float4*)(A + (size_t)(m0 + am) * K + kbase + kt + ak);
        if (reluA) {
            a4.x = fmaxf(a4.x, 0.f); a4.y = fmaxf(a4.y, 0.f);
            a4.z = fmaxf(a4.z, 0.f); a4.w = fmaxf(a4.w, 0.f);
        }
        As[ak][am] = a4.x; As[ak + 1][am] = a4.y;
        As[ak + 2][am] = a4.z; As[ak + 3][am] = a4.w;
        #pragma unroll
        for (int j = 0; j < 2; ++j) {
            int kr = j * 16 + bk;
            *(float4*)&Bs[kr][bc] = *(const float4*)(B + (size_t)(kbase + kt + kr) * N + n0 + bc);
        }
        __syncthreads();
        #pragma unroll
        for (int kk = 0; kk < FKS; ++kk) {
            float2 a2 = *(const float2*)&As[kk][tm];
            float4 b4 = *(const float4*)&Bs[kk][tn];
            acc[0][0] = fmaf(a2.x, b4.x, acc[0][0]); acc[0][1] = fmaf(a2.x, b4.y, acc[0][1]);
            acc[0][2] = fmaf(a2.x, b4.z, acc[0][2]); acc[0][3] = fmaf(a2.x, b4.w, acc[0][3]);
            acc[1][0] = fmaf(a2.y, b4.x, acc[1][0]); acc[1][1] = fmaf(a2.y, b4.y, acc[1][1]);
            acc[1][2] = fmaf(a2.y, b4.z, acc[1][2]); acc[1][3] = fmaf(a2.y, b4.w, acc[1][3]);
        }
        __syncthreads();
    }
    #pragma unroll
    for (int i = 0; i < 2; ++i) {
        float* cp = C + (size_t)(m0 + tm + i) * N + n0 + tn;
        #pragma unroll
        for (int j = 0; j < 4; ++j) atomAddF(cp + j, acc[i][j]);
    }
}

// ---------------- fusion output layer (relu on load of t2) ----------------
__global__ __launch_bounds__(256) void k_fout(
    const float* __restrict__ t2, const float* __restrict__ fW3,
    const float* __restrict__ fb3, float* __restrict__ out)
{
    int lane = threadIdx.x & 63;
    int row = blockIdx.x * 4 + (threadIdx.x >> 6);
    const float* tp = t2 + (size_t)row * 128;
    float p = fmaxf(tp[lane], 0.f) * fW3[lane] + fmaxf(tp[lane + 64], 0.f) * fW3[lane + 64];
    #pragma unroll
    for (int d = 1; d < 64; d <<= 1) p += __shfl_xor(p, d);
    if (lane == 0) out[row] = p + fb3[0];
}

extern "C" void kernel_launch(void* const* d_in, const int* in_sizes, int n_in,
                              void* d_out, int out_size, void* d_ws, size_t ws_size,
                              hipStream_t stream) {
    const float* x        = (const float*)d_in[0];
    const int*   ei       = (const int*)d_in[1];
    const int*   batch    = (const int*)d_in[2];
    const float* x_gen    = (const float*)d_in[3];
    const float* W1       = (const float*)d_in[4];
    const float* att_src1 = (const float*)d_in[5];
    const float* att_dst1 = (const float*)d_in[6];
    const float* bias1    = (const float*)d_in[7];
    const float* W2       = (const float*)d_in[8];
    const float* att_src2 = (const float*)d_in[9];
    const float* att_dst2 = (const float*)d_in[10];
    const float* bias2    = (const float*)d_in[11];
    const float* gW1      = (const float*)d_in[12];
    const float* gb1      = (const float*)d_in[13];
    const float* bn_gamma = (const float*)d_in[14];
    const float* bn_beta  = (const float*)d_in[15];
    const float* bn_mean  = (const float*)d_in[16];
    const float* bn_var   = (const float*)d_in[17];
    const float* gW2      = (const float*)d_in[18];
    const float* gb2      = (const float*)d_in[19];
    const float* fW1      = (const float*)d_in[20];
    const float* fb1      = (const float*)d_in[21];
    const float* fW2      = (const float*)d_in[22];
    const float* fb2      = (const float*)d_in[23];
    const float* fW3      = (const float*)d_in[24];
    const float* fb3      = (const float*)d_in[25];
    float* out = (float*)d_out;

    const int* srcv = ei;
    const int* dstv = ei + NE;

    char* w = (char*)d_ws;
    size_t off = 0;
    auto take = [&](size_t bytes) -> void* {
        void* p = w + off;
        off += (bytes + 255) & ~(size_t)255;
        return p;
    };
    __hip_bfloat16* hbuf = (__hip_bfloat16*)take((size_t)NN * GOUTD * 2);
    __hip_bfloat16* abuf = (__hip_bfloat16*)take((size_t)NN * GOUTD * 2);
    __hip_bfloat16* xb   = (__hip_bfloat16*)take((size_t)NN * 128 * 2);   // 16 MB
    __hip_bfloat16* w1t  = (__hip_bfloat16*)take((size_t)512 * 128 * 2);
    __hip_bfloat16* w2t  = (__hip_bfloat16*)take((size_t)512 * 512 * 2);
    float* asrc   = (float*)take((size_t)NN * 8 * 4);
    float* adst   = (float*)take((size_t)NN * 8 * 4);
    int*   rowptr = (int*)take((size_t)(NN + 1) * 4);
    int*   colI   = (int*)take((size_t)NE * 4);
    int*   deg    = (int*)take((size_t)NN * 4);
    int*   fill   = (int*)take((size_t)NN * 4);
    int*   bsum   = (int*)take(256 * 4);
    int*   gstart = (int*)take((NB + 1) * 4);
    float* cbuf = (float*)xb;                       // [2048, 1024]  8 MB (aliases xb; xb dead after gemm1)
    float* z1   = cbuf + (size_t)2048 * 1024;       // [2048, 128]   1 MB (zeroed by gemm2 tail)
    float* t1   = z1 + (size_t)2048 * 128;          // [2048, 256]   2 MB
    float* t2   = t1 + (size_t)2048 * 256;          // [2048, 128]   1 MB

    // ---- conversions + prep (merged), then CSR build ----
    k_cvt_prep<<<17920, 256, 0, stream>>>(x, W1, W2, xb, w1t, w2t, deg, fill, batch, gstart);
    k_hist<<<NE / 256, 256, 0, stream>>>(dstv, deg);
    k_scan_block<<<256, 256, 0, stream>>>(deg, rowptr, bsum);
    k_scan_add2<<<256, 256, 0, stream>>>(rowptr, bsum);
    k_scatter<<<NE / 256, 256, 0, stream>>>(srcv, dstv, rowptr, fill, colI);

    // ---- GAT layer 1 (GEMM computes h + attention logits fused) ----
    k_mfma_gemm<<<2048, 256, 0, stream>>>(xb, w1t, hbuf, 128, att_src1, att_dst1, asrc, adst,
                                          nullptr, nullptr, nullptr, nullptr, nullptr);
    k_gat_agg<<<NN / 4, 256, 0, stream>>>(hbuf, asrc, adst, rowptr, colI, bias1, abuf);

    // ---- GAT layer 2 (tail inits t1/t2 and zeroes z1; xb is dead by now) ----
    k_mfma_gemm<<<2048, 256, 0, stream>>>(abuf, w2t, hbuf, 512, att_src2, att_dst2, asrc, adst,
                                          t1, t2, fb1, fb2, z1);

    // ---- agg_pool (one block per graph) ----
    k_gat_agg_pool<<<NB, 256, 0, stream>>>(hbuf, asrc, adst, rowptr, colI, bias2,
                                           gstart, cbuf);

    // ---- genomic encoder as 2 tiled GEMMs ----
    k_geno1_sk<<<dim3(2, 64, 4), 256, 0, stream>>>(x_gen, gW1, z1);
    k_geno2<<<dim3(8, 64), 256, 0, stream>>>(z1, gW2, gb1, bn_mean, bn_var, bn_gamma,
                                             bn_beta, gb2, cbuf + 512);

    // ---- fusion MLP: 1024 -> 256 -> 128 -> 1 (split-K fp32, atomic accumulate) ----
    k_fgemm_sk<<<dim3(4, 64, 4), 256, 0, stream>>>(cbuf, fW1, t1, 256, 1024, 256, 0);
    k_fgemm_sk<<<dim3(2, 64, 4), 256, 0, stream>>>(t1, fW2, t2, 128, 256, 64, 1);
    k_fout<<<NB / 4, 256, 0, stream>>>(t2, fW3, fb3, out);
}

// Round 9
// 443.863 us; speedup vs baseline: 1.0139x; 1.0139x over previous
//
#include <hip/hip_runtime.h>
#include <hip/hip_bf16.h>
#include <cstdint>
#include <cstddef>

#define NN 65536
#define NE 262144
#define NB 2048
#define FIN 78
#define GOUTD 512

typedef __bf16 bf16x8 __attribute__((ext_vector_type(8)));
typedef float f32x4 __attribute__((ext_vector_type(4)));

__device__ __forceinline__ float leaky02(float x) { return x > 0.f ? x : 0.2f * x; }
__device__ __forceinline__ void atomAddF(float* p, float v) { unsafeAtomicAdd(p, v); }

// ---------------- CSR build ----------------
__global__ void k_hist(const int* __restrict__ dst, int* __restrict__ deg) {
    int i = blockIdx.x * 256 + threadIdx.x;
    if (i < NE) atomicAdd(&deg[dst[i]], 1);
}

__global__ void k_scan_block(const int* __restrict__ deg, int* __restrict__ ex, int* __restrict__ bsum) {
    __shared__ int s[256];
    int t = threadIdx.x; int g = blockIdx.x * 256 + t;
    int v = deg[g];
    s[t] = v; __syncthreads();
    for (int d = 1; d < 256; d <<= 1) {
        int x = (t >= d) ? s[t - d] : 0;
        __syncthreads();
        s[t] += x;
        __syncthreads();
    }
    ex[g] = s[t] - v;
    if (t == 255) bsum[blockIdx.x] = s[t];
}

// merged scan_bsum + scan_add
__global__ void k_scan_add2(int* __restrict__ rowptr, const int* __restrict__ bsum) {
    __shared__ int s[256];
    int t = threadIdx.x;
    int v = bsum[t];
    s[t] = v; __syncthreads();
    for (int d = 1; d < 256; d <<= 1) {
        int x = (t >= d) ? s[t - d] : 0;
        __syncthreads();
        s[t] += x;
        __syncthreads();
    }
    int prefix = (blockIdx.x == 0) ? 0 : s[blockIdx.x - 1];
    int i = blockIdx.x * 256 + t;
    rowptr[i] += prefix;
    if (i == 0) rowptr[NN] = NE;
}

__global__ void k_scatter(const int* __restrict__ src, const int* __restrict__ dst,
                          const int* __restrict__ rowptr, int* __restrict__ fill,
                          int* __restrict__ colI) {
    int i = blockIdx.x * 256 + threadIdx.x;
    if (i < NE) {
        int d = dst[i];
        int pos = rowptr[d] + atomicAdd(&fill[d], 1);
        colI[pos] = src[i];
    }
}

// ---------------- merged conversions + prep: x->xb, W1^T, W2^T, deg/fill zero, gstart ----------------
__global__ void k_cvt_prep(const float* __restrict__ x, const float* __restrict__ W1,
                           const float* __restrict__ W2, __hip_bfloat16* __restrict__ xb,
                           __hip_bfloat16* __restrict__ w1t, __hip_bfloat16* __restrict__ w2t,
                           int* __restrict__ deg, int* __restrict__ fill,
                           const int* __restrict__ batch, int* __restrict__ gstart)
{
    int blk = blockIdx.x;
    if (blk < 16384) {
        int i = blk * 256 + threadIdx.x;
        int row = i >> 6;
        int c = (i & 63) << 1;
        float v0 = (c < FIN) ? x[(size_t)row * FIN + c] : 0.f;
        float v1 = (c + 1 < FIN) ? x[(size_t)row * FIN + c + 1] : 0.f;
        __hip_bfloat16 o[2];
        o[0] = __float2bfloat16(v0);
        o[1] = __float2bfloat16(v1);
        *(uint32_t*)&xb[(size_t)row * 128 + c] = *(const uint32_t*)o;
    } else if (blk < 16640) {
        int i = (blk - 16384) * 256 + threadIdx.x;   // over 512*128
        int n = i >> 7, k = i & 127;
        w1t[i] = __float2bfloat16(k < FIN ? W1[(size_t)k * 512 + n] : 0.f);
    } else if (blk < 17664) {
        int i = (blk - 16640) * 256 + threadIdx.x;   // over 512*512
        int n = i >> 9, k = i & 511;
        w2t[i] = __float2bfloat16(W2[(size_t)k * 512 + n]);
    } else {
        int i = (blk - 17664) * 256 + threadIdx.x;   // prep over NN
        if (i < NN) {
            deg[i] = 0; fill[i] = 0;
            int cur = batch[i];
            int prev = (i == 0) ? -1 : batch[i - 1];
            for (int g = prev + 1; g <= cur; ++g) gstart[g] = i;
            if (i == NN - 1) {
                for (int g = cur + 1; g <= NB; ++g) gstart[g] = NN;
            }
        }
    }
}

// ---------------- bf16 MFMA GEMM + fused attention logits ----------------
// Tail (2nd call only, gated by t1!=nullptr): init t1 rows = fb1, t2 rows = fb2,
// zero z1 rows (for atomic-accumulate geno1 GEMM).
__global__ __launch_bounds__(256) void k_mfma_gemm(
    const __hip_bfloat16* __restrict__ A, const __hip_bfloat16* __restrict__ BT,
    __hip_bfloat16* __restrict__ C, int K,
    const float* __restrict__ att_src, const float* __restrict__ att_dst,
    float* __restrict__ a_src, float* __restrict__ a_dst,
    float* __restrict__ t1, float* __restrict__ t2,
    const float* __restrict__ fb1, const float* __restrict__ fb2,
    float* __restrict__ z1)
{
    __shared__ __hip_bfloat16 smem[128 * 128];          // 32 KB
    __hip_bfloat16* As = smem;
    __hip_bfloat16* Bs = smem + 128 * 64;
    int tid = threadIdx.x;
    int lane = tid & 63;
    int wave = tid >> 6;
    int id = blockIdx.x;
    int m0 = (((id >> 5) << 3) + (id & 7)) * 128;
    int n0 = ((id >> 3) & 3) * 128;
    int wm = (wave >> 1) * 64;
    int wn = (wave & 1) * 64;
    f32x4 acc[4][4] = {};

    int swz = lane & 7;

    for (int k0 = 0; k0 < K; k0 += 64) {
        #pragma unroll
        for (int c = 0; c < 4; ++c) {
            int off = c * 4096 + tid * 16;
            int r = off >> 7;
            int c16 = (off >> 4) & 7;
            int c16s = c16 ^ (r & 7);
            __builtin_amdgcn_global_load_lds(
                (const __attribute__((address_space(1))) void*)(A + (size_t)(m0 + r) * K + k0 + c16s * 8),
                (__attribute__((address_space(3))) void*)((char*)As + off), 16, 0, 0);
            __builtin_amdgcn_global_load_lds(
                (const __attribute__((address_space(1))) void*)(BT + (size_t)(n0 + r) * K + k0 + c16s * 8),
                (__attribute__((address_space(3))) void*)((char*)Bs + off), 16, 0, 0);
        }
        __syncthreads();
        #pragma unroll
        for (int kk = 0; kk < 64; kk += 32) {
            int c16r = (kk >> 3) + (lane >> 4);
            bf16x8 af[4], bfr[4];
            #pragma unroll
            for (int t = 0; t < 4; ++t) {
                int ra = wm + t * 16 + (lane & 15);
                int rb = wn + t * 16 + (lane & 15);
                af[t]  = *(const bf16x8*)((char*)As + ra * 128 + ((c16r ^ swz) << 4));
                bfr[t] = *(const bf16x8*)((char*)Bs + rb * 128 + ((c16r ^ swz) << 4));
            }
            #pragma unroll
            for (int i = 0; i < 4; ++i)
                #pragma unroll
                for (int j = 0; j < 4; ++j)
                    acc[i][j] = __builtin_amdgcn_mfma_f32_16x16x32_bf16(af[i], bfr[j], acc[i][j], 0, 0, 0);
        }
        __syncthreads();
    }

    // ---- epilogue: acc -> LDS (bank-swizzled) -> coalesced stores + fused attn dots ----
    int rowb = wm + ((lane >> 4) << 2);
    int colb = wn + (lane & 15);
    #pragma unroll
    for (int i = 0; i < 4; ++i) {
        #pragma unroll
        for (int j = 0; j < 4; ++j) {
            int cc = colb + j * 16;
            #pragma unroll
            for (int r = 0; r < 4; ++r) {
                int rr = rowb + i * 16 + r;
                int word = (cc >> 1) ^ (((rr >> 2) & 7) << 3);
                smem[rr * 128 + word * 2 + (cc & 1)] = __float2bfloat16(acc[i][j][r]);
            }
        }
    }
    __syncthreads();
    #pragma unroll
    for (int cc2 = 0; cc2 < 8; ++cc2) {
        int p = cc2 * 256 + tid;
        int rr = p >> 4;          // tile row 0..127
        int c16 = p & 15;         // 16B chunk (= 8 cols) within 128-col row
        int x = ((rr >> 2) & 7) << 3;
        bf16x8 v = *(const bf16x8*)((char*)smem + rr * 256 + ((((c16 << 2) ^ x)) << 2));
        *(bf16x8*)(C + (size_t)(m0 + rr) * 512 + n0 + c16 * 8) = v;
        // fused attention logits: chunks 0..7 = head (n0>>6), 8..15 = head+1
        const float* sp = att_src + n0 + c16 * 8;
        const float* dp = att_dst + n0 + c16 * 8;
        float4 s0 = *(const float4*)sp, s1 = *(const float4*)(sp + 4);
        float4 d0 = *(const float4*)dp, d1 = *(const float4*)(dp + 4);
        float sv[8] = {s0.x, s0.y, s0.z, s0.w, s1.x, s1.y, s1.z, s1.w};
        float dv[8] = {d0.x, d0.y, d0.z, d0.w, d1.x, d1.y, d1.z, d1.w};
        float ps = 0.f, pd = 0.f;
        #pragma unroll
        for (int k = 0; k < 8; ++k) {
            float f = (float)v[k];
            ps = fmaf(f, sv[k], ps);
            pd = fmaf(f, dv[k], pd);
        }
        #pragma unroll
        for (int d = 1; d < 8; d <<= 1) {
            ps += __shfl_xor(ps, d);
            pd += __shfl_xor(pd, d);
        }
        if ((c16 & 7) == 0) {
            int head = (n0 >> 6) + (c16 >> 3);
            a_src[(size_t)(m0 + rr) * 8 + head] = ps;
            a_dst[(size_t)(m0 + rr) * 8 + head] = pd;
        }
    }

    // ---- tail (layer-2 call only): init t1/t2 rows to bias, zero z1 row ----
    if (t1) {
        if (tid < 64)  *(float4*)(t1 + (size_t)id * 256 + tid * 4) = *(const float4*)(fb1 + tid * 4);
        if (tid < 32)  *(float4*)(t2 + (size_t)id * 128 + tid * 4) = *(const float4*)(fb2 + tid * 4);
        if (tid >= 64 && tid < 96)
            *(float4*)(z1 + (size_t)id * 128 + (tid - 64) * 4) = make_float4(0.f, 0.f, 0.f, 0.f);
    }
}

// ---------------- GAT aggregate (layer 1): single-pass, 2-edge pipeline ----------------
// (R8's 4-wide unroll regressed: VGPR 24->40, occupancy 62->41. Keep 2-wide.)
__global__ __launch_bounds__(256) void k_gat_agg(
    const __hip_bfloat16* __restrict__ h, const float* __restrict__ asrc,
    const float* __restrict__ adst, const int* __restrict__ rowptr,
    const int* __restrict__ colI, const float* __restrict__ bias,
    __hip_bfloat16* __restrict__ out)
{
    int lane = threadIdx.x & 63;
    int n = blockIdx.x * 4 + (threadIdx.x >> 6);
    int start = rowptr[n], end = rowptr[n + 1];
    int hh = lane >> 3;
    float adst_h = adst[n * 8 + hh];
    float acc[8];
    float wsum;
    {
        float w = __expf(leaky02(asrc[n * 8 + hh] + adst_h));   // self loop
        wsum = w;
        bf16x8 v = *(const bf16x8*)(h + (size_t)n * GOUTD + lane * 8);
        #pragma unroll
        for (int j = 0; j < 8; ++j) acc[j] = w * (float)v[j];
    }
    int i = start;
    for (; i + 1 < end; i += 2) {
        int s0 = colI[i];
        int s1 = colI[i + 1];
        float w0 = __expf(leaky02(asrc[s0 * 8 + hh] + adst_h));
        float w1 = __expf(leaky02(asrc[s1 * 8 + hh] + adst_h));
        bf16x8 v0 = *(const bf16x8*)(h + (size_t)s0 * GOUTD + lane * 8);
        bf16x8 v1 = *(const bf16x8*)(h + (size_t)s1 * GOUTD + lane * 8);
        wsum += w0 + w1;
        #pragma unroll
        for (int j = 0; j < 8; ++j)
            acc[j] = fmaf(w0, (float)v0[j], fmaf(w1, (float)v1[j], acc[j]));
    }
    if (i < end) {
        int s = colI[i];
        float w = __expf(leaky02(asrc[s * 8 + hh] + adst_h));
        wsum += w;
        bf16x8 v = *(const bf16x8*)(h + (size_t)s * GOUTD + lane * 8);
        #pragma unroll
        for (int j = 0; j < 8; ++j) acc[j] = fmaf(w, (float)v[j], acc[j]);
    }
    float rden = 1.f / (wsum + 1e-16f);
    const float* bp = bias + lane * 8;
    float4 b0 = *(const float4*)bp, b1 = *(const float4*)(bp + 4);
    float bb[8] = {b0.x, b0.y, b0.z, b0.w, b1.x, b1.y, b1.z, b1.w};
    __hip_bfloat16 o[8] __attribute__((aligned(16)));
    #pragma unroll
    for (int j = 0; j < 8; ++j) {
        float v = fmaf(acc[j], rden, bb[j]);
        v = (v > 0.f) ? v : (__expf(v) - 1.f);
        o[j] = __float2bfloat16(v);
    }
    *(bf16x8*)(out + (size_t)n * GOUTD + lane * 8) = *(const bf16x8*)o;
}

// ---------------- GAT aggregate layer 2 + fused mean-pool: ONE BLOCK PER GRAPH, 8 WAVES ----------------
// 2-wide edge pipeline (verified). vs R7: 512 threads = 8 waves/block -> node
// serial depth halves (~8 -> ~4 nodes/wave) and resident waves/CU rises toward
// the 32-wave cap (R7 measured 62% occ; R8's ILP attempt hit VGPR/occ cliff).
__global__ __launch_bounds__(512) void k_gat_agg_pool(
    const __hip_bfloat16* __restrict__ h, const float* __restrict__ asrc,
    const float* __restrict__ adst, const int* __restrict__ rowptr,
    const int* __restrict__ colI, const float* __restrict__ bias,
    const int* __restrict__ gstart, float* __restrict__ cfeat)
{
    __shared__ float red[8][512];
    int lane = threadIdx.x & 63;
    int wv = threadIdx.x >> 6;          // 0..7
    int g = blockIdx.x;
    int s = gstart[g], e = gstart[g + 1];
    int hh = lane >> 3;
    const float* bp = bias + lane * 8;
    float4 b0 = *(const float4*)bp, b1 = *(const float4*)(bp + 4);
    float bb[8] = {b0.x, b0.y, b0.z, b0.w, b1.x, b1.y, b1.z, b1.w};
    float psum[8] = {};
    for (int n = s + wv; n < e; n += 8) {
        int start = rowptr[n], end = rowptr[n + 1];
        float adst_h = adst[n * 8 + hh];
        float acc[8];
        float wsum;
        {
            float w = __expf(leaky02(asrc[n * 8 + hh] + adst_h));   // self loop
            wsum = w;
            bf16x8 v = *(const bf16x8*)(h + (size_t)n * GOUTD + lane * 8);
            #pragma unroll
            for (int j = 0; j < 8; ++j) acc[j] = w * (float)v[j];
        }
        int i = start;
        for (; i + 1 < end; i += 2) {
            int s0 = colI[i];
            int s1 = colI[i + 1];
            float w0 = __expf(leaky02(asrc[s0 * 8 + hh] + adst_h));
            float w1 = __expf(leaky02(asrc[s1 * 8 + hh] + adst_h));
            bf16x8 v0 = *(const bf16x8*)(h + (size_t)s0 * GOUTD + lane * 8);
            bf16x8 v1 = *(const bf16x8*)(h + (size_t)s1 * GOUTD + lane * 8);
            wsum += w0 + w1;
            #pragma unroll
            for (int j = 0; j < 8; ++j)
                acc[j] = fmaf(w0, (float)v0[j], fmaf(w1, (float)v1[j], acc[j]));
        }
        if (i < end) {
            int si = colI[i];
            float w = __expf(leaky02(asrc[si * 8 + hh] + adst_h));
            wsum += w;
            bf16x8 v = *(const bf16x8*)(h + (size_t)si * GOUTD + lane * 8);
            #pragma unroll
            for (int j = 0; j < 8; ++j) acc[j] = fmaf(w, (float)v[j], acc[j]);
        }
        float rden = 1.f / (wsum + 1e-16f);
        #pragma unroll
        for (int j = 0; j < 8; ++j) {
            float v = fmaf(acc[j], rden, bb[j]);
            v = (v > 0.f) ? v : (__expf(v) - 1.f);   // ELU
            psum[j] += v;
        }
    }
    #pragma unroll
    for (int j = 0; j < 8; ++j) red[wv][lane * 8 + j] = psum[j];
    __syncthreads();
    if (wv == 0) {
        float inv = 1.f / fmaxf((float)(e - s), 1.f);
        float* cp = cfeat + (size_t)g * 1024;
        #pragma unroll
        for (int j = 0; j < 8; ++j) {
            int c = lane * 8 + j;
            float sum = (red[0][c] + red[1][c]) + (red[2][c] + red[3][c])
                      + (red[4][c] + red[5][c]) + (red[6][c] + red[7][c]);
            cp[c] = sum * inv;
        }
    }
}

// ---------------- geno layer 1 as split-K GEMM: x_gen[2048,735] @ gW1[735,128] ----------------
__global__ __launch_bounds__(256) void k_geno1_sk(
    const float* __restrict__ A, const float* __restrict__ B, float* __restrict__ z1)
{
    __shared__ float As[32][34];
    __shared__ float Bs[32][68];
    int tid = threadIdx.x;
    int n0 = blockIdx.x * 64;            // 0 or 64 (N=128)
    int m0 = blockIdx.y * 32;
    int kbase = blockIdx.z * 192;
    int am = tid >> 3;
    int ak = (tid & 7) << 2;
    int bk = tid >> 4;
    int bc = (tid & 15) << 2;
    int tm = (tid >> 4) << 1;
    int tn = (tid & 15) << 2;
    float acc[2][4] = {};
    for (int kt = 0; kt < 192; kt += 32) {
        const float* ap = A + (size_t)(m0 + am) * 735 + kbase + kt + ak;
        int kg = kbase + kt + ak;
        As[ak][am]     = (kg     < 735) ? ap[0] : 0.f;
        As[ak + 1][am] = (kg + 1 < 735) ? ap[1] : 0.f;
        As[ak + 2][am] = (kg + 2 < 735) ? ap[2] : 0.f;
        As[ak + 3][am] = (kg + 3 < 735) ? ap[3] : 0.f;
        #pragma unroll
        for (int j = 0; j < 2; ++j) {
            int kr = j * 16 + bk;
            int kgb = kbase + kt + kr;
            float4 b4 = (kgb < 735) ? *(const float4*)(B + (size_t)kgb * 128 + n0 + bc)
                                    : make_float4(0.f, 0.f, 0.f, 0.f);
            *(float4*)&Bs[kr][bc] = b4;
        }
        __syncthreads();
        #pragma unroll
        for (int kk = 0; kk < 32; ++kk) {
            float2 a2 = *(const float2*)&As[kk][tm];
            float4 b4 = *(const float4*)&Bs[kk][tn];
            acc[0][0] = fmaf(a2.x, b4.x, acc[0][0]); acc[0][1] = fmaf(a2.x, b4.y, acc[0][1]);
            acc[0][2] = fmaf(a2.x, b4.z, acc[0][2]); acc[0][3] = fmaf(a2.x, b4.w, acc[0][3]);
            acc[1][0] = fmaf(a2.y, b4.x, acc[1][0]); acc[1][1] = fmaf(a2.y, b4.y, acc[1][1]);
            acc[1][2] = fmaf(a2.y, b4.z, acc[1][2]); acc[1][3] = fmaf(a2.y, b4.w, acc[1][3]);
        }
        __syncthreads();
    }
    #pragma unroll
    for (int i = 0; i < 2; ++i) {
        float* cp = z1 + (size_t)(m0 + tm + i) * 128 + n0 + tn;
        #pragma unroll
        for (int j = 0; j < 4; ++j) atomAddF(cp + j, acc[i][j]);
    }
}

// ---------------- geno layer 2 GEMM with fused BN+relu on A-load ----------------
__global__ __launch_bounds__(256) void k_geno2(
    const float* __restrict__ z1, const float* __restrict__ gW2,
    const float* __restrict__ gb1, const float* __restrict__ bn_mean,
    const float* __restrict__ bn_var, const float* __restrict__ bn_gamma,
    const float* __restrict__ bn_beta, const float* __restrict__ gb2,
    float* __restrict__ Cout)
{
    __shared__ float As[32][34];
    __shared__ float Bs[32][68];
    int tid = threadIdx.x;
    int n0 = blockIdx.x * 64;            // N=512 -> 8 n-blocks
    int m0 = blockIdx.y * 32;
    int am = tid >> 3;
    int ak = (tid & 7) << 2;
    int bk = tid >> 4;
    int bc = (tid & 15) << 2;
    int tm = (tid >> 4) << 1;
    int tn = (tid & 15) << 2;
    float acc[2][4] = {};
    for (int kt = 0; kt < 128; kt += 32) {
        int kg = kt + ak;
        float4 raw = *(const float4*)(z1 + (size_t)(m0 + am) * 128 + kg);
        float4 g1 = *(const float4*)(gb1 + kg);
        float4 mu = *(const float4*)(bn_mean + kg);
        float4 vr = *(const float4*)(bn_var + kg);
        float4 gm = *(const float4*)(bn_gamma + kg);
        float4 bt = *(const float4*)(bn_beta + kg);
        As[ak][am]     = fmaxf(fmaf(raw.x + g1.x - mu.x, rsqrtf(vr.x + 1e-5f) * gm.x, bt.x), 0.f);
        As[ak + 1][am] = fmaxf(fmaf(raw.y + g1.y - mu.y, rsqrtf(vr.y + 1e-5f) * gm.y, bt.y), 0.f);
        As[ak + 2][am] = fmaxf(fmaf(raw.z + g1.z - mu.z, rsqrtf(vr.z + 1e-5f) * gm.z, bt.z), 0.f);
        As[ak + 3][am] = fmaxf(fmaf(raw.w + g1.w - mu.w, rsqrtf(vr.w + 1e-5f) * gm.w, bt.w), 0.f);
        #pragma unroll
        for (int j = 0; j < 2; ++j) {
            int kr = j * 16 + bk;
            *(float4*)&Bs[kr][bc] = *(const float4*)(gW2 + (size_t)(kt + kr) * 512 + n0 + bc);
        }
        __syncthreads();
        #pragma unroll
        for (int kk = 0; kk < 32; ++kk) {
            float2 a2 = *(const float2*)&As[kk][tm];
            float4 b4 = *(const float4*)&Bs[kk][tn];
            acc[0][0] = fmaf(a2.x, b4.x, acc[0][0]); acc[0][1] = fmaf(a2.x, b4.y, acc[0][1]);
            acc[0][2] = fmaf(a2.x, b4.z, acc[0][2]); acc[0][3] = fmaf(a2.x, b4.w, acc[0][3]);
            acc[1][0] = fmaf(a2.y, b4.x, acc[1][0]); acc[1][1] = fmaf(a2.y, b4.y, acc[1][1]);
            acc[1][2] = fmaf(a2.y, b4.z, acc[1][2]); acc[1][3] = fmaf(a2.y, b4.w, acc[1][3]);
        }
        __syncthreads();
    }
    float4 bb = *(const float4*)(gb2 + n0 + tn);
    #pragma unroll
    for (int i = 0; i < 2; ++i) {
        float* cp = Cout + (size_t)(m0 + tm + i) * 1024 + n0 + tn;   // Cout pre-offset by 512
        *(float4*)cp = make_float4(fmaxf(acc[i][0] + bb.x, 0.f), fmaxf(acc[i][1] + bb.y, 0.f),
                                   fmaxf(acc[i][2] + bb.z, 0.f), fmaxf(acc[i][3] + bb.w, 0.f));
    }
}

// ---------------- fusion MLP layers 1-2: split-K fp32 GEMM, atomic accumulate ----------------
#define FBM 32
#define FBN 64
#define FKS 32

__global__ __launch_bounds__(256) void k_fgemm_sk(
    const float* __restrict__ A, const float* __restrict__ B,
    float* __restrict__ C, int N, int K, int KS, int reluA)
{
    __shared__ float As[FKS][FBM + 2];   // [k][m]
    __shared__ float Bs[FKS][FBN + 4];   // [k][n]
    int tid = threadIdx.x;
    int n0 = blockIdx.x * FBN;
    int m0 = blockIdx.y * FBM;
    int kbase = blockIdx.z * KS;
    int am = tid >> 3;
    int ak = (tid & 7) << 2;
    int bk = tid >> 4;
    int bc = (tid & 15) << 2;
    int tm = (tid >> 4) << 1;
    int tn = (tid & 15) << 2;
    float acc[2][4] = {};
    for (int kt = 0; kt < KS; kt += FKS) {
        float4 a4 = *(const float4*)(A + (size_t)(m0 + am) * K + kbase + kt + ak);
        if (reluA) {
            a4.x = fmaxf(a4.x, 0.f); a4.y = fmaxf(a4.y, 0.f);
            a4.z = fmaxf(a4.z, 0.f); a4.w = fmaxf(a4.w, 0.f);
        }
        As[ak][am] = a4.x; As[ak + 1][am] = a4.y;
        As[ak + 2][am] = a4.z; As[ak + 3][am] = a4.w;
        #pragma unroll
        for (int j = 0; j < 2; ++j) {
            int kr = j * 16 + bk;
            *(float4*)&Bs[kr][bc] = *(const float4*)(B + (size_t)(kbase + kt + kr) * N + n0 + bc);
        }
        __syncthreads();
        #pragma unroll
        for (int kk = 0; kk < FKS; ++kk) {
            float2 a2 = *(const float2*)&As[kk][tm];
            float4 b4 = *(const float4*)&Bs[kk][tn];
            acc[0][0] = fmaf(a2.x, b4.x, acc[0][0]); acc[0][1] = fmaf(a2.x, b4.y, acc[0][1]);
            acc[0][2] = fmaf(a2.x, b4.z, acc[0][2]); acc[0][3] = fmaf(a2.x, b4.w, acc[0][3]);
            acc[1][0] = fmaf(a2.y, b4.x, acc[1][0]); acc[1][1] = fmaf(a2.y, b4.y, acc[1][1]);
            acc[1][2] = fmaf(a2.y, b4.z, acc[1][2]); acc[1][3] = fmaf(a2.y, b4.w, acc[1][3]);
        }
        __syncthreads();
    }
    #pragma unroll
    for (int i = 0; i < 2; ++i) {
        float* cp = C + (size_t)(m0 + tm + i) * N + n0 + tn;
        #pragma unroll
        for (int j = 0; j < 4; ++j) atomAddF(cp + j, acc[i][j]);
    }
}

// ---------------- fusion output layer (relu on load of t2) ----------------
__global__ __launch_bounds__(256) void k_fout(
    const float* __restrict__ t2, const float* __restrict__ fW3,
    const float* __restrict__ fb3, float* __restrict__ out)
{
    int lane = threadIdx.x & 63;
    int row = blockIdx.x * 4 + (threadIdx.x >> 6);
    const float* tp = t2 + (size_t)row * 128;
    float p = fmaxf(tp[lane], 0.f) * fW3[lane] + fmaxf(tp[lane + 64], 0.f) * fW3[lane + 64];
    #pragma unroll
    for (int d = 1; d < 64; d <<= 1) p += __shfl_xor(p, d);
    if (lane == 0) out[row] = p + fb3[0];
}

extern "C" void kernel_launch(void* const* d_in, const int* in_sizes, int n_in,
                              void* d_out, int out_size, void* d_ws, size_t ws_size,
                              hipStream_t stream) {
    const float* x        = (const float*)d_in[0];
    const int*   ei       = (const int*)d_in[1];
    const int*   batch    = (const int*)d_in[2];
    const float* x_gen    = (const float*)d_in[3];
    const float* W1       = (const float*)d_in[4];
    const float* att_src1 = (const float*)d_in[5];
    const float* att_dst1 = (const float*)d_in[6];
    const float* bias1    = (const float*)d_in[7];
    const float* W2       = (const float*)d_in[8];
    const float* att_src2 = (const float*)d_in[9];
    const float* att_dst2 = (const float*)d_in[10];
    const float* bias2    = (const float*)d_in[11];
    const float* gW1      = (const float*)d_in[12];
    const float* gb1      = (const float*)d_in[13];
    const float* bn_gamma = (const float*)d_in[14];
    const float* bn_beta  = (const float*)d_in[15];
    const float* bn_mean  = (const float*)d_in[16];
    const float* bn_var   = (const float*)d_in[17];
    const float* gW2      = (const float*)d_in[18];
    const float* gb2      = (const float*)d_in[19];
    const float* fW1      = (const float*)d_in[20];
    const float* fb1      = (const float*)d_in[21];
    const float* fW2      = (const float*)d_in[22];
    const float* fb2      = (const float*)d_in[23];
    const float* fW3      = (const float*)d_in[24];
    const float* fb3      = (const float*)d_in[25];
    float* out = (float*)d_out;

    const int* srcv = ei;
    const int* dstv = ei + NE;

    char* w = (char*)d_ws;
    size_t off = 0;
    auto take = [&](size_t bytes) -> void* {
        void* p = w + off;
        off += (bytes + 255) & ~(size_t)255;
        return p;
    };
    __hip_bfloat16* hbuf = (__hip_bfloat16*)take((size_t)NN * GOUTD * 2);
    __hip_bfloat16* abuf = (__hip_bfloat16*)take((size_t)NN * GOUTD * 2);
    __hip_bfloat16* xb   = (__hip_bfloat16*)take((size_t)NN * 128 * 2);   // 16 MB
    __hip_bfloat16* w1t  = (__hip_bfloat16*)take((size_t)512 * 128 * 2);
    __hip_bfloat16* w2t  = (__hip_bfloat16*)take((size_t)512 * 512 * 2);
    float* asrc   = (float*)take((size_t)NN * 8 * 4);
    float* adst   = (float*)take((size_t)NN * 8 * 4);
    int*   rowptr = (int*)take((size_t)(NN + 1) * 4);
    int*   colI   = (int*)take((size_t)NE * 4);
    int*   deg    = (int*)take((size_t)NN * 4);
    int*   fill   = (int*)take((size_t)NN * 4);
    int*   bsum   = (int*)take(256 * 4);
    int*   gstart = (int*)take((NB + 1) * 4);
    float* cbuf = (float*)xb;                       // [2048, 1024]  8 MB (aliases xb; xb dead after gemm1)
    float* z1   = cbuf + (size_t)2048 * 1024;       // [2048, 128]   1 MB (zeroed by gemm2 tail)
    float* t1   = z1 + (size_t)2048 * 128;          // [2048, 256]   2 MB
    float* t2   = t1 + (size_t)2048 * 256;          // [2048, 128]   1 MB

    // ---- conversions + prep (merged), then CSR build ----
    k_cvt_prep<<<17920, 256, 0, stream>>>(x, W1, W2, xb, w1t, w2t, deg, fill, batch, gstart);
    k_hist<<<NE / 256, 256, 0, stream>>>(dstv, deg);
    k_scan_block<<<256, 256, 0, stream>>>(deg, rowptr, bsum);
    k_scan_add2<<<256, 256, 0, stream>>>(rowptr, bsum);
    k_scatter<<<NE / 256, 256, 0, stream>>>(srcv, dstv, rowptr, fill, colI);

    // ---- GAT layer 1 (GEMM computes h + attention logits fused) ----
    k_mfma_gemm<<<2048, 256, 0, stream>>>(xb, w1t, hbuf, 128, att_src1, att_dst1, asrc, adst,
                                          nullptr, nullptr, nullptr, nullptr, nullptr);
    k_gat_agg<<<NN / 4, 256, 0, stream>>>(hbuf, asrc, adst, rowptr, colI, bias1, abuf);

    // ---- GAT layer 2 (tail inits t1/t2 and zeroes z1; xb is dead by now) ----
    k_mfma_gemm<<<2048, 256, 0, stream>>>(abuf, w2t, hbuf, 512, att_src2, att_dst2, asrc, adst,
                                          t1, t2, fb1, fb2, z1);

    // ---- agg_pool (one block per graph, 8 waves) ----
    k_gat_agg_pool<<<NB, 512, 0, stream>>>(hbuf, asrc, adst, rowptr, colI, bias2,
                                           gstart, cbuf);

    // ---- genomic encoder as 2 tiled GEMMs ----
    k_geno1_sk<<<dim3(2, 64, 4), 256, 0, stream>>>(x_gen, gW1, z1);
    k_geno2<<<dim3(8, 64), 256, 0, stream>>>(z1, gW2, gb1, bn_mean, bn_var, bn_gamma,
                                             bn_beta, gb2, cbuf + 512);

    // ---- fusion MLP: 1024 -> 256 -> 128 -> 1 (split-K fp32, atomic accumulate) ----
    k_fgemm_sk<<<dim3(4, 64, 4), 256, 0, stream>>>(cbuf, fW1, t1, 256, 1024, 256, 0);
    k_fgemm_sk<<<dim3(2, 64, 4), 256, 0, stream>>>(t1, fW2, t2, 128, 256, 64, 1);
    k_fout<<<NB / 4, 256, 0, stream>>>(t2, fW3, fb3, out);
}

// Round 10
// 438.626 us; speedup vs baseline: 1.0260x; 1.0119x over previous
//
#include <hip/hip_runtime.h>
#include <hip/hip_bf16.h>
#include <cstdint>
#include <cstddef>

#define NN 65536
#define NE 262144
#define NB 2048
#define FIN 78
#define GOUTD 512

typedef __bf16 bf16x8 __attribute__((ext_vector_type(8)));
typedef float f32x4 __attribute__((ext_vector_type(4)));

__device__ __forceinline__ float leaky02(float x) { return x > 0.f ? x : 0.2f * x; }
__device__ __forceinline__ void atomAddF(float* p, float v) { unsafeAtomicAdd(p, v); }

// ---------------- CSR build ----------------
__global__ void k_hist(const int* __restrict__ dst, int* __restrict__ deg) {
    int i = blockIdx.x * 256 + threadIdx.x;
    if (i < NE) atomicAdd(&deg[dst[i]], 1);
}

__global__ void k_scan_block(const int* __restrict__ deg, int* __restrict__ ex, int* __restrict__ bsum) {
    __shared__ int s[256];
    int t = threadIdx.x; int g = blockIdx.x * 256 + t;
    int v = deg[g];
    s[t] = v; __syncthreads();
    for (int d = 1; d < 256; d <<= 1) {
        int x = (t >= d) ? s[t - d] : 0;
        __syncthreads();
        s[t] += x;
        __syncthreads();
    }
    ex[g] = s[t] - v;
    if (t == 255) bsum[blockIdx.x] = s[t];
}

// merged scan_bsum + scan_add
__global__ void k_scan_add2(int* __restrict__ rowptr, const int* __restrict__ bsum) {
    __shared__ int s[256];
    int t = threadIdx.x;
    int v = bsum[t];
    s[t] = v; __syncthreads();
    for (int d = 1; d < 256; d <<= 1) {
        int x = (t >= d) ? s[t - d] : 0;
        __syncthreads();
        s[t] += x;
        __syncthreads();
    }
    int prefix = (blockIdx.x == 0) ? 0 : s[blockIdx.x - 1];
    int i = blockIdx.x * 256 + t;
    rowptr[i] += prefix;
    if (i == 0) rowptr[NN] = NE;
}

__global__ void k_scatter(const int* __restrict__ src, const int* __restrict__ dst,
                          const int* __restrict__ rowptr, int* __restrict__ fill,
                          int* __restrict__ colI) {
    int i = blockIdx.x * 256 + threadIdx.x;
    if (i < NE) {
        int d = dst[i];
        int pos = rowptr[d] + atomicAdd(&fill[d], 1);
        colI[pos] = src[i];
    }
}

// ---------------- merged conversions + prep: x->xb, W1^T, W2^T, deg/fill zero, gstart ----------------
__global__ void k_cvt_prep(const float* __restrict__ x, const float* __restrict__ W1,
                           const float* __restrict__ W2, __hip_bfloat16* __restrict__ xb,
                           __hip_bfloat16* __restrict__ w1t, __hip_bfloat16* __restrict__ w2t,
                           int* __restrict__ deg, int* __restrict__ fill,
                           const int* __restrict__ batch, int* __restrict__ gstart)
{
    int blk = blockIdx.x;
    if (blk < 16384) {
        int i = blk * 256 + threadIdx.x;
        int row = i >> 6;
        int c = (i & 63) << 1;
        float v0 = (c < FIN) ? x[(size_t)row * FIN + c] : 0.f;
        float v1 = (c + 1 < FIN) ? x[(size_t)row * FIN + c + 1] : 0.f;
        __hip_bfloat16 o[2];
        o[0] = __float2bfloat16(v0);
        o[1] = __float2bfloat16(v1);
        *(uint32_t*)&xb[(size_t)row * 128 + c] = *(const uint32_t*)o;
    } else if (blk < 16640) {
        int i = (blk - 16384) * 256 + threadIdx.x;   // over 512*128
        int n = i >> 7, k = i & 127;
        w1t[i] = __float2bfloat16(k < FIN ? W1[(size_t)k * 512 + n] : 0.f);
    } else if (blk < 17664) {
        int i = (blk - 16640) * 256 + threadIdx.x;   // over 512*512
        int n = i >> 9, k = i & 511;
        w2t[i] = __float2bfloat16(W2[(size_t)k * 512 + n]);
    } else {
        int i = (blk - 17664) * 256 + threadIdx.x;   // prep over NN
        if (i < NN) {
            deg[i] = 0; fill[i] = 0;
            int cur = batch[i];
            int prev = (i == 0) ? -1 : batch[i - 1];
            for (int g = prev + 1; g <= cur; ++g) gstart[g] = i;
            if (i == NN - 1) {
                for (int g = cur + 1; g <= NB; ++g) gstart[g] = NN;
            }
        }
    }
}

// ---------------- bf16 MFMA GEMM (128x256 tile, 8 waves) + fused attention logits ----------------
// vs previous 128x128/4-wave version: A-tile re-reads drop 4x -> 2x (gemm2 A
// traffic 256->128 MB). Per-wave compute identical (64x64 acc[4][4], same XOR
// swizzle: row&7 == lane&7 holds for 256 B-rows too). Epilogue runs in two
// 128-col passes through the 32KB staging region.
// Grid 1024: id -> m_t=(id>>4)*8+(id&7), n_t=(id>>3)&1 (same-A pair 8 apart -> same XCD).
// Tail (2nd call, t1!=nullptr): rows 2id,2id+1 of t1=fb1,t2=fb2,z1=0.
__global__ __launch_bounds__(512) void k_mfma_gemm(
    const __hip_bfloat16* __restrict__ A, const __hip_bfloat16* __restrict__ BT,
    __hip_bfloat16* __restrict__ C, int K,
    const float* __restrict__ att_src, const float* __restrict__ att_dst,
    float* __restrict__ a_src, float* __restrict__ a_dst,
    float* __restrict__ t1, float* __restrict__ t2,
    const float* __restrict__ fb1, const float* __restrict__ fb2,
    float* __restrict__ z1)
{
    __shared__ __hip_bfloat16 smem[128 * 64 + 256 * 64];   // A 16KB + B 32KB = 48KB
    __hip_bfloat16* As = smem;
    __hip_bfloat16* Bs = smem + 128 * 64;
    int tid = threadIdx.x;
    int lane = tid & 63;
    int wave = tid >> 6;          // 0..7
    int wr = wave >> 2;           // 0..1 (m)
    int wc = wave & 3;            // 0..3 (n)
    int id = blockIdx.x;
    int m0 = (((id >> 4) << 3) + (id & 7)) * 128;
    int n0 = ((id >> 3) & 1) * 256;
    int wm = wr * 64;
    int wn = wc * 64;
    f32x4 acc[4][4] = {};

    int swz = lane & 7;

    for (int k0 = 0; k0 < K; k0 += 64) {
        #pragma unroll
        for (int c = 0; c < 2; ++c) {          // A: 16KB, 2 rounds
            int off = c * 8192 + tid * 16;
            int r = off >> 7;
            int c16 = (off >> 4) & 7;
            int c16s = c16 ^ (r & 7);
            __builtin_amdgcn_global_load_lds(
                (const __attribute__((address_space(1))) void*)(A + (size_t)(m0 + r) * K + k0 + c16s * 8),
                (__attribute__((address_space(3))) void*)((char*)As + off), 16, 0, 0);
        }
        #pragma unroll
        for (int c = 0; c < 4; ++c) {          // B: 32KB, 4 rounds
            int off = c * 8192 + tid * 16;
            int r = off >> 7;                  // 0..255
            int c16 = (off >> 4) & 7;
            int c16s = c16 ^ (r & 7);
            __builtin_amdgcn_global_load_lds(
                (const __attribute__((address_space(1))) void*)(BT + (size_t)(n0 + r) * K + k0 + c16s * 8),
                (__attribute__((address_space(3))) void*)((char*)Bs + off), 16, 0, 0);
        }
        __syncthreads();
        #pragma unroll
        for (int kk = 0; kk < 64; kk += 32) {
            int c16r = (kk >> 3) + (lane >> 4);
            bf16x8 af[4], bfr[4];
            #pragma unroll
            for (int t = 0; t < 4; ++t) {
                int ra = wm + t * 16 + (lane & 15);
                int rb = wn + t * 16 + (lane & 15);
                af[t]  = *(const bf16x8*)((char*)As + ra * 128 + ((c16r ^ swz) << 4));
                bfr[t] = *(const bf16x8*)((char*)Bs + rb * 128 + ((c16r ^ swz) << 4));
            }
            #pragma unroll
            for (int i = 0; i < 4; ++i)
                #pragma unroll
                for (int j = 0; j < 4; ++j)
                    acc[i][j] = __builtin_amdgcn_mfma_f32_16x16x32_bf16(af[i], bfr[j], acc[i][j], 0, 0, 0);
        }
        __syncthreads();
    }

    // ---- epilogue: two 128-col passes; acc -> LDS (bank-swizzled) -> coalesced stores + attn ----
    #pragma unroll
    for (int p = 0; p < 2; ++p) {
        if ((wc >> 1) == p) {
            int rowb = wm + ((lane >> 4) << 2);
            int colb = (wc & 1) * 64 + (lane & 15);
            #pragma unroll
            for (int i = 0; i < 4; ++i) {
                #pragma unroll
                for (int j = 0; j < 4; ++j) {
                    int cc = colb + j * 16;
                    #pragma unroll
                    for (int r = 0; r < 4; ++r) {
                        int rr = rowb + i * 16 + r;
                        int word = (cc >> 1) ^ (((rr >> 2) & 7) << 3);
                        smem[rr * 128 + word * 2 + (cc & 1)] = __float2bfloat16(acc[i][j][r]);
                    }
                }
            }
        }
        __syncthreads();
        int cb = n0 + p * 128;      // global col base of this pass
        #pragma unroll
        for (int cc2 = 0; cc2 < 4; ++cc2) {
            int pi = cc2 * 512 + tid;
            int rr = pi >> 4;          // tile row 0..127
            int c16 = pi & 15;         // 16B chunk within 128-col pass
            int x = ((rr >> 2) & 7) << 3;
            bf16x8 v = *(const bf16x8*)((char*)smem + rr * 256 + ((((c16 << 2) ^ x)) << 2));
            *(bf16x8*)(C + (size_t)(m0 + rr) * 512 + cb + c16 * 8) = v;
            const float* sp = att_src + cb + c16 * 8;
            const float* dp = att_dst + cb + c16 * 8;
            float4 s0 = *(const float4*)sp, s1 = *(const float4*)(sp + 4);
            float4 d0 = *(const float4*)dp, d1 = *(const float4*)(dp + 4);
            float sv[8] = {s0.x, s0.y, s0.z, s0.w, s1.x, s1.y, s1.z, s1.w};
            float dv[8] = {d0.x, d0.y, d0.z, d0.w, d1.x, d1.y, d1.z, d1.w};
            float ps = 0.f, pd = 0.f;
            #pragma unroll
            for (int k = 0; k < 8; ++k) {
                float f = (float)v[k];
                ps = fmaf(f, sv[k], ps);
                pd = fmaf(f, dv[k], pd);
            }
            #pragma unroll
            for (int d = 1; d < 8; d <<= 1) {
                ps += __shfl_xor(ps, d);
                pd += __shfl_xor(pd, d);
            }
            if ((c16 & 7) == 0) {
                int head = (cb >> 6) + (c16 >> 3);
                a_src[(size_t)(m0 + rr) * 8 + head] = ps;
                a_dst[(size_t)(m0 + rr) * 8 + head] = pd;
            }
        }
        __syncthreads();
    }

    // ---- tail (layer-2 call only): rows 2id, 2id+1: t1=fb1, t2=fb2, z1=0 ----
    if (t1) {
        if (tid < 128) {
            int r = 2 * id + (tid >> 6), e = tid & 63;
            *(float4*)(t1 + (size_t)r * 256 + e * 4) = *(const float4*)(fb1 + e * 4);
        } else if (tid < 192) {
            int q = tid - 128, r = 2 * id + (q >> 5), e = q & 31;
            *(float4*)(t2 + (size_t)r * 128 + e * 4) = *(const float4*)(fb2 + e * 4);
        } else if (tid < 256) {
            int q = tid - 192, r = 2 * id + (q >> 5), e = q & 31;
            *(float4*)(z1 + (size_t)r * 128 + e * 4) = make_float4(0.f, 0.f, 0.f, 0.f);
        }
    }
}

// ---------------- GAT aggregate (layer 1): single-pass, 2-edge pipeline (R7-verified) ----------------
__global__ __launch_bounds__(256) void k_gat_agg(
    const __hip_bfloat16* __restrict__ h, const float* __restrict__ asrc,
    const float* __restrict__ adst, const int* __restrict__ rowptr,
    const int* __restrict__ colI, const float* __restrict__ bias,
    __hip_bfloat16* __restrict__ out)
{
    int lane = threadIdx.x & 63;
    int n = blockIdx.x * 4 + (threadIdx.x >> 6);
    int start = rowptr[n], end = rowptr[n + 1];
    int hh = lane >> 3;
    float adst_h = adst[n * 8 + hh];
    float acc[8];
    float wsum;
    {
        float w = __expf(leaky02(asrc[n * 8 + hh] + adst_h));   // self loop
        wsum = w;
        bf16x8 v = *(const bf16x8*)(h + (size_t)n * GOUTD + lane * 8);
        #pragma unroll
        for (int j = 0; j < 8; ++j) acc[j] = w * (float)v[j];
    }
    int i = start;
    for (; i + 1 < end; i += 2) {
        int s0 = colI[i];
        int s1 = colI[i + 1];
        float w0 = __expf(leaky02(asrc[s0 * 8 + hh] + adst_h));
        float w1 = __expf(leaky02(asrc[s1 * 8 + hh] + adst_h));
        bf16x8 v0 = *(const bf16x8*)(h + (size_t)s0 * GOUTD + lane * 8);
        bf16x8 v1 = *(const bf16x8*)(h + (size_t)s1 * GOUTD + lane * 8);
        wsum += w0 + w1;
        #pragma unroll
        for (int j = 0; j < 8; ++j)
            acc[j] = fmaf(w0, (float)v0[j], fmaf(w1, (float)v1[j], acc[j]));
    }
    if (i < end) {
        int s = colI[i];
        float w = __expf(leaky02(asrc[s * 8 + hh] + adst_h));
        wsum += w;
        bf16x8 v = *(const bf16x8*)(h + (size_t)s * GOUTD + lane * 8);
        #pragma unroll
        for (int j = 0; j < 8; ++j) acc[j] = fmaf(w, (float)v[j], acc[j]);
    }
    float rden = 1.f / (wsum + 1e-16f);
    const float* bp = bias + lane * 8;
    float4 b0 = *(const float4*)bp, b1 = *(const float4*)(bp + 4);
    float bb[8] = {b0.x, b0.y, b0.z, b0.w, b1.x, b1.y, b1.z, b1.w};
    __hip_bfloat16 o[8] __attribute__((aligned(16)));
    #pragma unroll
    for (int j = 0; j < 8; ++j) {
        float v = fmaf(acc[j], rden, bb[j]);
        v = (v > 0.f) ? v : (__expf(v) - 1.f);
        o[j] = __float2bfloat16(v);
    }
    *(bf16x8*)(out + (size_t)n * GOUTD + lane * 8) = *(const bf16x8*)o;
}

// ---------------- GAT aggregate layer 2 + fused mean-pool: ONE BLOCK PER GRAPH (R7-verified) ----------------
__global__ __launch_bounds__(256) void k_gat_agg_pool(
    const __hip_bfloat16* __restrict__ h, const float* __restrict__ asrc,
    const float* __restrict__ adst, const int* __restrict__ rowptr,
    const int* __restrict__ colI, const float* __restrict__ bias,
    const int* __restrict__ gstart, float* __restrict__ cfeat)
{
    __shared__ float red[4][512];
    int lane = threadIdx.x & 63;
    int wv = threadIdx.x >> 6;
    int g = blockIdx.x;
    int s = gstart[g], e = gstart[g + 1];
    int hh = lane >> 3;
    const float* bp = bias + lane * 8;
    float4 b0 = *(const float4*)bp, b1 = *(const float4*)(bp + 4);
    float bb[8] = {b0.x, b0.y, b0.z, b0.w, b1.x, b1.y, b1.z, b1.w};
    float psum[8] = {};
    for (int n = s + wv; n < e; n += 4) {
        int start = rowptr[n], end = rowptr[n + 1];
        float adst_h = adst[n * 8 + hh];
        float acc[8];
        float wsum;
        {
            float w = __expf(leaky02(asrc[n * 8 + hh] + adst_h));   // self loop
            wsum = w;
            bf16x8 v = *(const bf16x8*)(h + (size_t)n * GOUTD + lane * 8);
            #pragma unroll
            for (int j = 0; j < 8; ++j) acc[j] = w * (float)v[j];
        }
        int i = start;
        for (; i + 1 < end; i += 2) {
            int s0 = colI[i];
            int s1 = colI[i + 1];
            float w0 = __expf(leaky02(asrc[s0 * 8 + hh] + adst_h));
            float w1 = __expf(leaky02(asrc[s1 * 8 + hh] + adst_h));
            bf16x8 v0 = *(const bf16x8*)(h + (size_t)s0 * GOUTD + lane * 8);
            bf16x8 v1 = *(const bf16x8*)(h + (size_t)s1 * GOUTD + lane * 8);
            wsum += w0 + w1;
            #pragma unroll
            for (int j = 0; j < 8; ++j)
                acc[j] = fmaf(w0, (float)v0[j], fmaf(w1, (float)v1[j], acc[j]));
        }
        if (i < end) {
            int si = colI[i];
            float w = __expf(leaky02(asrc[si * 8 + hh] + adst_h));
            wsum += w;
            bf16x8 v = *(const bf16x8*)(h + (size_t)si * GOUTD + lane * 8);
            #pragma unroll
            for (int j = 0; j < 8; ++j) acc[j] = fmaf(w, (float)v[j], acc[j]);
        }
        float rden = 1.f / (wsum + 1e-16f);
        #pragma unroll
        for (int j = 0; j < 8; ++j) {
            float v = fmaf(acc[j], rden, bb[j]);
            v = (v > 0.f) ? v : (__expf(v) - 1.f);   // ELU
            psum[j] += v;
        }
    }
    #pragma unroll
    for (int j = 0; j < 8; ++j) red[wv][lane * 8 + j] = psum[j];
    __syncthreads();
    if (wv == 0) {
        float inv = 1.f / fmaxf((float)(e - s), 1.f);
        float* cp = cfeat + (size_t)g * 1024;
        #pragma unroll
        for (int j = 0; j < 8; ++j) {
            int c = lane * 8 + j;
            cp[c] = (red[0][c] + red[1][c] + red[2][c] + red[3][c]) * inv;
        }
    }
}

// ---------------- geno layer 1 as split-K GEMM: x_gen[2048,735] @ gW1[735,128] ----------------
__global__ __launch_bounds__(256) void k_geno1_sk(
    const float* __restrict__ A, const float* __restrict__ B, float* __restrict__ z1)
{
    __shared__ float As[32][34];
    __shared__ float Bs[32][68];
    int tid = threadIdx.x;
    int n0 = blockIdx.x * 64;            // 0 or 64 (N=128)
    int m0 = blockIdx.y * 32;
    int kbase = blockIdx.z * 192;
    int am = tid >> 3;
    int ak = (tid & 7) << 2;
    int bk = tid >> 4;
    int bc = (tid & 15) << 2;
    int tm = (tid >> 4) << 1;
    int tn = (tid & 15) << 2;
    float acc[2][4] = {};
    for (int kt = 0; kt < 192; kt += 32) {
        const float* ap = A + (size_t)(m0 + am) * 735 + kbase + kt + ak;
        int kg = kbase + kt + ak;
        As[ak][am]     = (kg     < 735) ? ap[0] : 0.f;
        As[ak + 1][am] = (kg + 1 < 735) ? ap[1] : 0.f;
        As[ak + 2][am] = (kg + 2 < 735) ? ap[2] : 0.f;
        As[ak + 3][am] = (kg + 3 < 735) ? ap[3] : 0.f;
        #pragma unroll
        for (int j = 0; j < 2; ++j) {
            int kr = j * 16 + bk;
            int kgb = kbase + kt + kr;
            float4 b4 = (kgb < 735) ? *(const float4*)(B + (size_t)kgb * 128 + n0 + bc)
                                    : make_float4(0.f, 0.f, 0.f, 0.f);
            *(float4*)&Bs[kr][bc] = b4;
        }
        __syncthreads();
        #pragma unroll
        for (int kk = 0; kk < 32; ++kk) {
            float2 a2 = *(const float2*)&As[kk][tm];
            float4 b4 = *(const float4*)&Bs[kk][tn];
            acc[0][0] = fmaf(a2.x, b4.x, acc[0][0]); acc[0][1] = fmaf(a2.x, b4.y, acc[0][1]);
            acc[0][2] = fmaf(a2.x, b4.z, acc[0][2]); acc[0][3] = fmaf(a2.x, b4.w, acc[0][3]);
            acc[1][0] = fmaf(a2.y, b4.x, acc[1][0]); acc[1][1] = fmaf(a2.y, b4.y, acc[1][1]);
            acc[1][2] = fmaf(a2.y, b4.z, acc[1][2]); acc[1][3] = fmaf(a2.y, b4.w, acc[1][3]);
        }
        __syncthreads();
    }
    #pragma unroll
    for (int i = 0; i < 2; ++i) {
        float* cp = z1 + (size_t)(m0 + tm + i) * 128 + n0 + tn;
        #pragma unroll
        for (int j = 0; j < 4; ++j) atomAddF(cp + j, acc[i][j]);
    }
}

// ---------------- geno layer 2 GEMM with fused BN+relu on A-load ----------------
__global__ __launch_bounds__(256) void k_geno2(
    const float* __restrict__ z1, const float* __restrict__ gW2,
    const float* __restrict__ gb1, const float* __restrict__ bn_mean,
    const float* __restrict__ bn_var, const float* __restrict__ bn_gamma,
    const float* __restrict__ bn_beta, const float* __restrict__ gb2,
    float* __restrict__ Cout)
{
    __shared__ float As[32][34];
    __shared__ float Bs[32][68];
    int tid = threadIdx.x;
    int n0 = blockIdx.x * 64;            // N=512 -> 8 n-blocks
    int m0 = blockIdx.y * 32;
    int am = tid >> 3;
    int ak = (tid & 7) << 2;
    int bk = tid >> 4;
    int bc = (tid & 15) << 2;
    int tm = (tid >> 4) << 1;
    int tn = (tid & 15) << 2;
    float acc[2][4] = {};
    for (int kt = 0; kt < 128; kt += 32) {
        int kg = kt + ak;
        float4 raw = *(const float4*)(z1 + (size_t)(m0 + am) * 128 + kg);
        float4 g1 = *(const float4*)(gb1 + kg);
        float4 mu = *(const float4*)(bn_mean + kg);
        float4 vr = *(const float4*)(bn_var + kg);
        float4 gm = *(const float4*)(bn_gamma + kg);
        float4 bt = *(const float4*)(bn_beta + kg);
        As[ak][am]     = fmaxf(fmaf(raw.x + g1.x - mu.x, rsqrtf(vr.x + 1e-5f) * gm.x, bt.x), 0.f);
        As[ak + 1][am] = fmaxf(fmaf(raw.y + g1.y - mu.y, rsqrtf(vr.y + 1e-5f) * gm.y, bt.y), 0.f);
        As[ak + 2][am] = fmaxf(fmaf(raw.z + g1.z - mu.z, rsqrtf(vr.z + 1e-5f) * gm.z, bt.z), 0.f);
        As[ak + 3][am] = fmaxf(fmaf(raw.w + g1.w - mu.w, rsqrtf(vr.w + 1e-5f) * gm.w, bt.w), 0.f);
        #pragma unroll
        for (int j = 0; j < 2; ++j) {
            int kr = j * 16 + bk;
            *(float4*)&Bs[kr][bc] = *(const float4*)(gW2 + (size_t)(kt + kr) * 512 + n0 + bc);
        }
        __syncthreads();
        #pragma unroll
        for (int kk = 0; kk < 32; ++kk) {
            float2 a2 = *(const float2*)&As[kk][tm];
            float4 b4 = *(const float4*)&Bs[kk][tn];
            acc[0][0] = fmaf(a2.x, b4.x, acc[0][0]); acc[0][1] = fmaf(a2.x, b4.y, acc[0][1]);
            acc[0][2] = fmaf(a2.x, b4.z, acc[0][2]); acc[0][3] = fmaf(a2.x, b4.w, acc[0][3]);
            acc[1][0] = fmaf(a2.y, b4.x, acc[1][0]); acc[1][1] = fmaf(a2.y, b4.y, acc[1][1]);
            acc[1][2] = fmaf(a2.y, b4.z, acc[1][2]); acc[1][3] = fmaf(a2.y, b4.w, acc[1][3]);
        }
        __syncthreads();
    }
    float4 bb = *(const float4*)(gb2 + n0 + tn);
    #pragma unroll
    for (int i = 0; i < 2; ++i) {
        float* cp = Cout + (size_t)(m0 + tm + i) * 1024 + n0 + tn;   // Cout pre-offset by 512
        *(float4*)cp = make_float4(fmaxf(acc[i][0] + bb.x, 0.f), fmaxf(acc[i][1] + bb.y, 0.f),
                                   fmaxf(acc[i][2] + bb.z, 0.f), fmaxf(acc[i][3] + bb.w, 0.f));
    }
}

// ---------------- fusion MLP layers 1-2: split-K fp32 GEMM, atomic accumulate ----------------
#define FBM 32
#define FBN 64
#define FKS 32

__global__ __launch_bounds__(256) void k_fgemm_sk(
    const float* __restrict__ A, const float* __restrict__ B,
    float* __restrict__ C, int N, int K, int KS, int reluA)
{
    __shared__ float As[FKS][FBM + 2];   // [k][m]
    __shared__ float Bs[FKS][FBN + 4];   // [k][n]
    int tid = threadIdx.x;
    int n0 = blockIdx.x * FBN;
    int m0 = blockIdx.y * FBM;
    int kbase = blockIdx.z * KS;
    int am = tid >> 3;
    int ak = (tid & 7) << 2;
    int bk = tid >> 4;
    int bc = (tid & 15) << 2;
    int tm = (tid >> 4) << 1;
    int tn = (tid & 15) << 2;
    float acc[2][4] = {};
    for (int kt = 0; kt < KS; kt += FKS) {
        float4 a4 = *(const float4*)(A + (size_t)(m0 + am) * K + kbase + kt + ak);
        if (reluA) {
            a4.x = fmaxf(a4.x, 0.f); a4.y = fmaxf(a4.y, 0.f);
            a4.z = fmaxf(a4.z, 0.f); a4.w = fmaxf(a4.w, 0.f);
        }
        As[ak][am] = a4.x; As[ak + 1][am] = a4.y;
        As[ak + 2][am] = a4.z; As[ak + 3][am] = a4.w;
        #pragma unroll
        for (int j = 0; j < 2; ++j) {
            int kr = j * 16 + bk;
            *(float4*)&Bs[kr][bc] = *(const float4*)(B + (size_t)(kbase + kt + kr) * N + n0 + bc);
        }
        __syncthreads();
        #pragma unroll
        for (int kk = 0; kk < FKS; ++kk) {
            float2 a2 = *(const float2*)&As[kk][tm];
            float4 b4 = *(const float4*)&Bs[kk][tn];
            acc[0][0] = fmaf(a2.x, b4.x, acc[0][0]); acc[0][1] = fmaf(a2.x, b4.y, acc[0][1]);
            acc[0][2] = fmaf(a2.x, b4.z, acc[0][2]); acc[0][3] = fmaf(a2.x, b4.w, acc[0][3]);
            acc[1][0] = fmaf(a2.y, b4.x, acc[1][0]); acc[1][1] = fmaf(a2.y, b4.y, acc[1][1]);
            acc[1][2] = fmaf(a2.y, b4.z, acc[1][2]); acc[1][3] = fmaf(a2.y, b4.w, acc[1][3]);
        }
        __syncthreads();
    }
    #pragma unroll
    for (int i = 0; i < 2; ++i) {
        float* cp = C + (size_t)(m0 + tm + i) * N + n0 + tn;
        #pragma unroll
        for (int j = 0; j < 4; ++j) atomAddF(cp + j, acc[i][j]);
    }
}

// ---------------- fusion output layer (relu on load of t2) ----------------
__global__ __launch_bounds__(256) void k_fout(
    const float* __restrict__ t2, const float* __restrict__ fW3,
    const float* __restrict__ fb3, float* __restrict__ out)
{
    int lane = threadIdx.x & 63;
    int row = blockIdx.x * 4 + (threadIdx.x >> 6);
    const float* tp = t2 + (size_t)row * 128;
    float p = fmaxf(tp[lane], 0.f) * fW3[lane] + fmaxf(tp[lane + 64], 0.f) * fW3[lane + 64];
    #pragma unroll
    for (int d = 1; d < 64; d <<= 1) p += __shfl_xor(p, d);
    if (lane == 0) out[row] = p + fb3[0];
}

extern "C" void kernel_launch(void* const* d_in, const int* in_sizes, int n_in,
                              void* d_out, int out_size, void* d_ws, size_t ws_size,
                              hipStream_t stream) {
    const float* x        = (const float*)d_in[0];
    const int*   ei       = (const int*)d_in[1];
    const int*   batch    = (const int*)d_in[2];
    const float* x_gen    = (const float*)d_in[3];
    const float* W1       = (const float*)d_in[4];
    const float* att_src1 = (const float*)d_in[5];
    const float* att_dst1 = (const float*)d_in[6];
    const float* bias1    = (const float*)d_in[7];
    const float* W2       = (const float*)d_in[8];
    const float* att_src2 = (const float*)d_in[9];
    const float* att_dst2 = (const float*)d_in[10];
    const float* bias2    = (const float*)d_in[11];
    const float* gW1      = (const float*)d_in[12];
    const float* gb1      = (const float*)d_in[13];
    const float* bn_gamma = (const float*)d_in[14];
    const float* bn_beta  = (const float*)d_in[15];
    const float* bn_mean  = (const float*)d_in[16];
    const float* bn_var   = (const float*)d_in[17];
    const float* gW2      = (const float*)d_in[18];
    const float* gb2      = (const float*)d_in[19];
    const float* fW1      = (const float*)d_in[20];
    const float* fb1      = (const float*)d_in[21];
    const float* fW2      = (const float*)d_in[22];
    const float* fb2      = (const float*)d_in[23];
    const float* fW3      = (const float*)d_in[24];
    const float* fb3      = (const float*)d_in[25];
    float* out = (float*)d_out;

    const int* srcv = ei;
    const int* dstv = ei + NE;

    char* w = (char*)d_ws;
    size_t off = 0;
    auto take = [&](size_t bytes) -> void* {
        void* p = w + off;
        off += (bytes + 255) & ~(size_t)255;
        return p;
    };
    __hip_bfloat16* hbuf = (__hip_bfloat16*)take((size_t)NN * GOUTD * 2);
    __hip_bfloat16* abuf = (__hip_bfloat16*)take((size_t)NN * GOUTD * 2);
    __hip_bfloat16* xb   = (__hip_bfloat16*)take((size_t)NN * 128 * 2);   // 16 MB
    __hip_bfloat16* w1t  = (__hip_bfloat16*)take((size_t)512 * 128 * 2);
    __hip_bfloat16* w2t  = (__hip_bfloat16*)take((size_t)512 * 512 * 2);
    float* asrc   = (float*)take((size_t)NN * 8 * 4);
    float* adst   = (float*)take((size_t)NN * 8 * 4);
    int*   rowptr = (int*)take((size_t)(NN + 1) * 4);
    int*   colI   = (int*)take((size_t)NE * 4);
    int*   deg    = (int*)take((size_t)NN * 4);
    int*   fill   = (int*)take((size_t)NN * 4);
    int*   bsum   = (int*)take(256 * 4);
    int*   gstart = (int*)take((NB + 1) * 4);
    float* cbuf = (float*)xb;                       // [2048, 1024]  8 MB (aliases xb; xb dead after gemm1)
    float* z1   = cbuf + (size_t)2048 * 1024;       // [2048, 128]   1 MB (zeroed by gemm2 tail)
    float* t1   = z1 + (size_t)2048 * 128;          // [2048, 256]   2 MB
    float* t2   = t1 + (size_t)2048 * 256;          // [2048, 128]   1 MB

    // ---- conversions + prep (merged), then CSR build ----
    k_cvt_prep<<<17920, 256, 0, stream>>>(x, W1, W2, xb, w1t, w2t, deg, fill, batch, gstart);
    k_hist<<<NE / 256, 256, 0, stream>>>(dstv, deg);
    k_scan_block<<<256, 256, 0, stream>>>(deg, rowptr, bsum);
    k_scan_add2<<<256, 256, 0, stream>>>(rowptr, bsum);
    k_scatter<<<NE / 256, 256, 0, stream>>>(srcv, dstv, rowptr, fill, colI);

    // ---- GAT layer 1 (GEMM computes h + attention logits fused) ----
    k_mfma_gemm<<<1024, 512, 0, stream>>>(xb, w1t, hbuf, 128, att_src1, att_dst1, asrc, adst,
                                          nullptr, nullptr, nullptr, nullptr, nullptr);
    k_gat_agg<<<NN / 4, 256, 0, stream>>>(hbuf, asrc, adst, rowptr, colI, bias1, abuf);

    // ---- GAT layer 2 (tail inits t1/t2 and zeroes z1; xb is dead by now) ----
    k_mfma_gemm<<<1024, 512, 0, stream>>>(abuf, w2t, hbuf, 512, att_src2, att_dst2, asrc, adst,
                                          t1, t2, fb1, fb2, z1);

    // ---- agg_pool (one block per graph, R7-verified 256-thread form) ----
    k_gat_agg_pool<<<NB, 256, 0, stream>>>(hbuf, asrc, adst, rowptr, colI, bias2,
                                           gstart, cbuf);

    // ---- genomic encoder as 2 tiled GEMMs ----
    k_geno1_sk<<<dim3(2, 64, 4), 256, 0, stream>>>(x_gen, gW1, z1);
    k_geno2<<<dim3(8, 64), 256, 0, stream>>>(z1, gW2, gb1, bn_mean, bn_var, bn_gamma,
                                             bn_beta, gb2, cbuf + 512);

    // ---- fusion MLP: 1024 -> 256 -> 128 -> 1 (split-K fp32, atomic accumulate) ----
    k_fgemm_sk<<<dim3(4, 64, 4), 256, 0, stream>>>(cbuf, fW1, t1, 256, 1024, 256, 0);
    k_fgemm_sk<<<dim3(2, 64, 4), 256, 0, stream>>>(t1, fW2, t2, 128, 256, 64, 1);
    k_fout<<<NB / 4, 256, 0, stream>>>(t2, fW3, fb3, out);
}

// Round 11
// 433.541 us; speedup vs baseline: 1.0380x; 1.0117x over previous
//
#include <hip/hip_runtime.h>
#include <hip/hip_bf16.h>
#include <cstdint>
#include <cstddef>

#define NN 65536
#define NE 262144
#define NB 2048
#define FIN 78
#define GOUTD 512

typedef __bf16 bf16x8 __attribute__((ext_vector_type(8)));
typedef float f32x4 __attribute__((ext_vector_type(4)));

__device__ __forceinline__ float leaky02(float x) { return x > 0.f ? x : 0.2f * x; }
__device__ __forceinline__ void atomAddF(float* p, float v) { unsafeAtomicAdd(p, v); }

// ---------------- CSR build ----------------
__global__ void k_hist(const int* __restrict__ dst, int* __restrict__ deg) {
    int i = blockIdx.x * 256 + threadIdx.x;
    if (i < NE) atomicAdd(&deg[dst[i]], 1);
}

__global__ void k_scan_block(const int* __restrict__ deg, int* __restrict__ ex, int* __restrict__ bsum) {
    __shared__ int s[256];
    int t = threadIdx.x; int g = blockIdx.x * 256 + t;
    int v = deg[g];
    s[t] = v; __syncthreads();
    for (int d = 1; d < 256; d <<= 1) {
        int x = (t >= d) ? s[t - d] : 0;
        __syncthreads();
        s[t] += x;
        __syncthreads();
    }
    ex[g] = s[t] - v;
    if (t == 255) bsum[blockIdx.x] = s[t];
}

// merged scan_bsum + scan_add
__global__ void k_scan_add2(int* __restrict__ rowptr, const int* __restrict__ bsum) {
    __shared__ int s[256];
    int t = threadIdx.x;
    int v = bsum[t];
    s[t] = v; __syncthreads();
    for (int d = 1; d < 256; d <<= 1) {
        int x = (t >= d) ? s[t - d] : 0;
        __syncthreads();
        s[t] += x;
        __syncthreads();
    }
    int prefix = (blockIdx.x == 0) ? 0 : s[blockIdx.x - 1];
    int i = blockIdx.x * 256 + t;
    rowptr[i] += prefix;
    if (i == 0) rowptr[NN] = NE;
}

// ---------------- merged conversions + prep: x->xb, W1^T, W2^T, deg/fill zero, gstart ----------------
__global__ void k_cvt_prep(const float* __restrict__ x, const float* __restrict__ W1,
                           const float* __restrict__ W2, __hip_bfloat16* __restrict__ xb,
                           __hip_bfloat16* __restrict__ w1t, __hip_bfloat16* __restrict__ w2t,
                           int* __restrict__ deg, int* __restrict__ fill,
                           const int* __restrict__ batch, int* __restrict__ gstart)
{
    int blk = blockIdx.x;
    if (blk < 16384) {
        int i = blk * 256 + threadIdx.x;
        int row = i >> 6;
        int c = (i & 63) << 1;
        // FIN even, c even -> if c<FIN then c+1<FIN; row stride 312B, 8B-aligned float2
        float2 v = (c < FIN) ? *(const float2*)(x + (size_t)row * FIN + c)
                             : make_float2(0.f, 0.f);
        __hip_bfloat16 o[2];
        o[0] = __float2bfloat16(v.x);
        o[1] = __float2bfloat16(v.y);
        *(uint32_t*)&xb[(size_t)row * 128 + c] = *(const uint32_t*)o;
    } else if (blk < 16640) {
        int i = (blk - 16384) * 256 + threadIdx.x;   // over 512*128
        int n = i >> 7, k = i & 127;
        w1t[i] = __float2bfloat16(k < FIN ? W1[(size_t)k * 512 + n] : 0.f);
    } else if (blk < 17664) {
        int i = (blk - 16640) * 256 + threadIdx.x;   // over 512*512
        int n = i >> 9, k = i & 511;
        w2t[i] = __float2bfloat16(W2[(size_t)k * 512 + n]);
    } else {
        int i = (blk - 17664) * 256 + threadIdx.x;   // prep over NN
        if (i < NN) {
            deg[i] = 0; fill[i] = 0;
            int cur = batch[i];
            int prev = (i == 0) ? -1 : batch[i - 1];
            for (int g = prev + 1; g <= cur; ++g) gstart[g] = i;
            if (i == NN - 1) {
                for (int g = cur + 1; g <= NB; ++g) gstart[g] = NN;
            }
        }
    }
}

// ---------------- gemm1: bf16 MFMA GEMM (128x128, 256thr, R7-verified) + attn logits ----------------
// For K=128 the main loop is only 2 K-steps; the epilogue dominates -> 2048
// blocks (4/CU) give it parallelism (R10's 1024 fat blocks regressed this).
// Blocks >= 2048 run the CSR scatter (needs rowptr/fill only; completes before
// agg1 by kernel boundary) -- saves a launch and overlaps scatter with gemm tail.
__global__ __launch_bounds__(256) void k_mfma_gemm1(
    const __hip_bfloat16* __restrict__ A, const __hip_bfloat16* __restrict__ BT,
    __hip_bfloat16* __restrict__ C, int K,
    const float* __restrict__ att_src, const float* __restrict__ att_dst,
    float* __restrict__ a_src, float* __restrict__ a_dst,
    const int* __restrict__ srcv, const int* __restrict__ dstv,
    const int* __restrict__ rowptr, int* __restrict__ fill, int* __restrict__ colI)
{
    if (blockIdx.x >= 2048) {            // ---- scatter branch ----
        int i = (blockIdx.x - 2048) * 256 + threadIdx.x;
        if (i < NE) {
            int d = dstv[i];
            int pos = rowptr[d] + atomicAdd(&fill[d], 1);
            colI[pos] = srcv[i];
        }
        return;
    }
    __shared__ __hip_bfloat16 smem[128 * 128];          // 32 KB
    __hip_bfloat16* As = smem;
    __hip_bfloat16* Bs = smem + 128 * 64;
    int tid = threadIdx.x;
    int lane = tid & 63;
    int wave = tid >> 6;
    int id = blockIdx.x;
    int m0 = (((id >> 5) << 3) + (id & 7)) * 128;
    int n0 = ((id >> 3) & 3) * 128;
    int wm = (wave >> 1) * 64;
    int wn = (wave & 1) * 64;
    f32x4 acc[4][4] = {};

    int swz = lane & 7;

    for (int k0 = 0; k0 < K; k0 += 64) {
        #pragma unroll
        for (int c = 0; c < 4; ++c) {
            int off = c * 4096 + tid * 16;
            int r = off >> 7;
            int c16 = (off >> 4) & 7;
            int c16s = c16 ^ (r & 7);
            __builtin_amdgcn_global_load_lds(
                (const __attribute__((address_space(1))) void*)(A + (size_t)(m0 + r) * K + k0 + c16s * 8),
                (__attribute__((address_space(3))) void*)((char*)As + off), 16, 0, 0);
            __builtin_amdgcn_global_load_lds(
                (const __attribute__((address_space(1))) void*)(BT + (size_t)(n0 + r) * K + k0 + c16s * 8),
                (__attribute__((address_space(3))) void*)((char*)Bs + off), 16, 0, 0);
        }
        __syncthreads();
        #pragma unroll
        for (int kk = 0; kk < 64; kk += 32) {
            int c16r = (kk >> 3) + (lane >> 4);
            bf16x8 af[4], bfr[4];
            #pragma unroll
            for (int t = 0; t < 4; ++t) {
                int ra = wm + t * 16 + (lane & 15);
                int rb = wn + t * 16 + (lane & 15);
                af[t]  = *(const bf16x8*)((char*)As + ra * 128 + ((c16r ^ swz) << 4));
                bfr[t] = *(const bf16x8*)((char*)Bs + rb * 128 + ((c16r ^ swz) << 4));
            }
            #pragma unroll
            for (int i = 0; i < 4; ++i)
                #pragma unroll
                for (int j = 0; j < 4; ++j)
                    acc[i][j] = __builtin_amdgcn_mfma_f32_16x16x32_bf16(af[i], bfr[j], acc[i][j], 0, 0, 0);
        }
        __syncthreads();
    }

    // ---- epilogue: acc -> LDS (bank-swizzled) -> coalesced stores + fused attn dots ----
    int rowb = wm + ((lane >> 4) << 2);
    int colb = wn + (lane & 15);
    #pragma unroll
    for (int i = 0; i < 4; ++i) {
        #pragma unroll
        for (int j = 0; j < 4; ++j) {
            int cc = colb + j * 16;
            #pragma unroll
            for (int r = 0; r < 4; ++r) {
                int rr = rowb + i * 16 + r;
                int word = (cc >> 1) ^ (((rr >> 2) & 7) << 3);
                smem[rr * 128 + word * 2 + (cc & 1)] = __float2bfloat16(acc[i][j][r]);
            }
        }
    }
    __syncthreads();
    #pragma unroll
    for (int cc2 = 0; cc2 < 8; ++cc2) {
        int p = cc2 * 256 + tid;
        int rr = p >> 4;
        int c16 = p & 15;
        int x = ((rr >> 2) & 7) << 3;
        bf16x8 v = *(const bf16x8*)((char*)smem + rr * 256 + ((((c16 << 2) ^ x)) << 2));
        *(bf16x8*)(C + (size_t)(m0 + rr) * 512 + n0 + c16 * 8) = v;
        const float* sp = att_src + n0 + c16 * 8;
        const float* dp = att_dst + n0 + c16 * 8;
        float4 s0 = *(const float4*)sp, s1 = *(const float4*)(sp + 4);
        float4 d0 = *(const float4*)dp, d1 = *(const float4*)(dp + 4);
        float sv[8] = {s0.x, s0.y, s0.z, s0.w, s1.x, s1.y, s1.z, s1.w};
        float dv[8] = {d0.x, d0.y, d0.z, d0.w, d1.x, d1.y, d1.z, d1.w};
        float ps = 0.f, pd = 0.f;
        #pragma unroll
        for (int k = 0; k < 8; ++k) {
            float f = (float)v[k];
            ps = fmaf(f, sv[k], ps);
            pd = fmaf(f, dv[k], pd);
        }
        #pragma unroll
        for (int d = 1; d < 8; d <<= 1) {
            ps += __shfl_xor(ps, d);
            pd += __shfl_xor(pd, d);
        }
        if ((c16 & 7) == 0) {
            int head = (n0 >> 6) + (c16 >> 3);
            a_src[(size_t)(m0 + rr) * 8 + head] = ps;
            a_dst[(size_t)(m0 + rr) * 8 + head] = pd;
        }
    }
}

// ---------------- gemm2: bf16 MFMA GEMM (128x256 tile, 8 waves, R10-verified) + attn ----------------
// Tail: init t1 rows = fb1, t2 rows = fb2, zero z1 rows.
__global__ __launch_bounds__(512) void k_mfma_gemm(
    const __hip_bfloat16* __restrict__ A, const __hip_bfloat16* __restrict__ BT,
    __hip_bfloat16* __restrict__ C, int K,
    const float* __restrict__ att_src, const float* __restrict__ att_dst,
    float* __restrict__ a_src, float* __restrict__ a_dst,
    float* __restrict__ t1, float* __restrict__ t2,
    const float* __restrict__ fb1, const float* __restrict__ fb2,
    float* __restrict__ z1)
{
    __shared__ __hip_bfloat16 smem[128 * 64 + 256 * 64];   // A 16KB + B 32KB = 48KB
    __hip_bfloat16* As = smem;
    __hip_bfloat16* Bs = smem + 128 * 64;
    int tid = threadIdx.x;
    int lane = tid & 63;
    int wave = tid >> 6;          // 0..7
    int wr = wave >> 2;           // 0..1 (m)
    int wc = wave & 3;            // 0..3 (n)
    int id = blockIdx.x;
    int m0 = (((id >> 4) << 3) + (id & 7)) * 128;
    int n0 = ((id >> 3) & 1) * 256;
    int wm = wr * 64;
    int wn = wc * 64;
    f32x4 acc[4][4] = {};

    int swz = lane & 7;

    for (int k0 = 0; k0 < K; k0 += 64) {
        #pragma unroll
        for (int c = 0; c < 2; ++c) {          // A: 16KB, 2 rounds
            int off = c * 8192 + tid * 16;
            int r = off >> 7;
            int c16 = (off >> 4) & 7;
            int c16s = c16 ^ (r & 7);
            __builtin_amdgcn_global_load_lds(
                (const __attribute__((address_space(1))) void*)(A + (size_t)(m0 + r) * K + k0 + c16s * 8),
                (__attribute__((address_space(3))) void*)((char*)As + off), 16, 0, 0);
        }
        #pragma unroll
        for (int c = 0; c < 4; ++c) {          // B: 32KB, 4 rounds
            int off = c * 8192 + tid * 16;
            int r = off >> 7;                  // 0..255
            int c16 = (off >> 4) & 7;
            int c16s = c16 ^ (r & 7);
            __builtin_amdgcn_global_load_lds(
                (const __attribute__((address_space(1))) void*)(BT + (size_t)(n0 + r) * K + k0 + c16s * 8),
                (__attribute__((address_space(3))) void*)((char*)Bs + off), 16, 0, 0);
        }
        __syncthreads();
        #pragma unroll
        for (int kk = 0; kk < 64; kk += 32) {
            int c16r = (kk >> 3) + (lane >> 4);
            bf16x8 af[4], bfr[4];
            #pragma unroll
            for (int t = 0; t < 4; ++t) {
                int ra = wm + t * 16 + (lane & 15);
                int rb = wn + t * 16 + (lane & 15);
                af[t]  = *(const bf16x8*)((char*)As + ra * 128 + ((c16r ^ swz) << 4));
                bfr[t] = *(const bf16x8*)((char*)Bs + rb * 128 + ((c16r ^ swz) << 4));
            }
            #pragma unroll
            for (int i = 0; i < 4; ++i)
                #pragma unroll
                for (int j = 0; j < 4; ++j)
                    acc[i][j] = __builtin_amdgcn_mfma_f32_16x16x32_bf16(af[i], bfr[j], acc[i][j], 0, 0, 0);
        }
        __syncthreads();
    }

    // ---- epilogue: two 128-col passes ----
    #pragma unroll
    for (int p = 0; p < 2; ++p) {
        if ((wc >> 1) == p) {
            int rowb = wm + ((lane >> 4) << 2);
            int colb = (wc & 1) * 64 + (lane & 15);
            #pragma unroll
            for (int i = 0; i < 4; ++i) {
                #pragma unroll
                for (int j = 0; j < 4; ++j) {
                    int cc = colb + j * 16;
                    #pragma unroll
                    for (int r = 0; r < 4; ++r) {
                        int rr = rowb + i * 16 + r;
                        int word = (cc >> 1) ^ (((rr >> 2) & 7) << 3);
                        smem[rr * 128 + word * 2 + (cc & 1)] = __float2bfloat16(acc[i][j][r]);
                    }
                }
            }
        }
        __syncthreads();
        int cb = n0 + p * 128;
        #pragma unroll
        for (int cc2 = 0; cc2 < 4; ++cc2) {
            int pi = cc2 * 512 + tid;
            int rr = pi >> 4;
            int c16 = pi & 15;
            int x = ((rr >> 2) & 7) << 3;
            bf16x8 v = *(const bf16x8*)((char*)smem + rr * 256 + ((((c16 << 2) ^ x)) << 2));
            *(bf16x8*)(C + (size_t)(m0 + rr) * 512 + cb + c16 * 8) = v;
            const float* sp = att_src + cb + c16 * 8;
            const float* dp = att_dst + cb + c16 * 8;
            float4 s0 = *(const float4*)sp, s1 = *(const float4*)(sp + 4);
            float4 d0 = *(const float4*)dp, d1 = *(const float4*)(dp + 4);
            float sv[8] = {s0.x, s0.y, s0.z, s0.w, s1.x, s1.y, s1.z, s1.w};
            float dv[8] = {d0.x, d0.y, d0.z, d0.w, d1.x, d1.y, d1.z, d1.w};
            float ps = 0.f, pd = 0.f;
            #pragma unroll
            for (int k = 0; k < 8; ++k) {
                float f = (float)v[k];
                ps = fmaf(f, sv[k], ps);
                pd = fmaf(f, dv[k], pd);
            }
            #pragma unroll
            for (int d = 1; d < 8; d <<= 1) {
                ps += __shfl_xor(ps, d);
                pd += __shfl_xor(pd, d);
            }
            if ((c16 & 7) == 0) {
                int head = (cb >> 6) + (c16 >> 3);
                a_src[(size_t)(m0 + rr) * 8 + head] = ps;
                a_dst[(size_t)(m0 + rr) * 8 + head] = pd;
            }
        }
        __syncthreads();
    }

    // ---- tail: rows 2id, 2id+1: t1=fb1, t2=fb2, z1=0 ----
    if (t1) {
        if (tid < 128) {
            int r = 2 * id + (tid >> 6), e = tid & 63;
            *(float4*)(t1 + (size_t)r * 256 + e * 4) = *(const float4*)(fb1 + e * 4);
        } else if (tid < 192) {
            int q = tid - 128, r = 2 * id + (q >> 5), e = q & 31;
            *(float4*)(t2 + (size_t)r * 128 + e * 4) = *(const float4*)(fb2 + e * 4);
        } else if (tid < 256) {
            int q = tid - 192, r = 2 * id + (q >> 5), e = q & 31;
            *(float4*)(z1 + (size_t)r * 128 + e * 4) = make_float4(0.f, 0.f, 0.f, 0.f);
        }
    }
}

// ---------------- GAT aggregate (layer 1): single-pass, 2-edge pipeline (verified) ----------------
__global__ __launch_bounds__(256) void k_gat_agg(
    const __hip_bfloat16* __restrict__ h, const float* __restrict__ asrc,
    const float* __restrict__ adst, const int* __restrict__ rowptr,
    const int* __restrict__ colI, const float* __restrict__ bias,
    __hip_bfloat16* __restrict__ out)
{
    int lane = threadIdx.x & 63;
    int n = blockIdx.x * 4 + (threadIdx.x >> 6);
    int start = rowptr[n], end = rowptr[n + 1];
    int hh = lane >> 3;
    float adst_h = adst[n * 8 + hh];
    float acc[8];
    float wsum;
    {
        float w = __expf(leaky02(asrc[n * 8 + hh] + adst_h));   // self loop
        wsum = w;
        bf16x8 v = *(const bf16x8*)(h + (size_t)n * GOUTD + lane * 8);
        #pragma unroll
        for (int j = 0; j < 8; ++j) acc[j] = w * (float)v[j];
    }
    int i = start;
    for (; i + 1 < end; i += 2) {
        int s0 = colI[i];
        int s1 = colI[i + 1];
        float w0 = __expf(leaky02(asrc[s0 * 8 + hh] + adst_h));
        float w1 = __expf(leaky02(asrc[s1 * 8 + hh] + adst_h));
        bf16x8 v0 = *(const bf16x8*)(h + (size_t)s0 * GOUTD + lane * 8);
        bf16x8 v1 = *(const bf16x8*)(h + (size_t)s1 * GOUTD + lane * 8);
        wsum += w0 + w1;
        #pragma unroll
        for (int j = 0; j < 8; ++j)
            acc[j] = fmaf(w0, (float)v0[j], fmaf(w1, (float)v1[j], acc[j]));
    }
    if (i < end) {
        int s = colI[i];
        float w = __expf(leaky02(asrc[s * 8 + hh] + adst_h));
        wsum += w;
        bf16x8 v = *(const bf16x8*)(h + (size_t)s * GOUTD + lane * 8);
        #pragma unroll
        for (int j = 0; j < 8; ++j) acc[j] = fmaf(w, (float)v[j], acc[j]);
    }
    float rden = 1.f / (wsum + 1e-16f);
    const float* bp = bias + lane * 8;
    float4 b0 = *(const float4*)bp, b1 = *(const float4*)(bp + 4);
    float bb[8] = {b0.x, b0.y, b0.z, b0.w, b1.x, b1.y, b1.z, b1.w};
    __hip_bfloat16 o[8] __attribute__((aligned(16)));
    #pragma unroll
    for (int j = 0; j < 8; ++j) {
        float v = fmaf(acc[j], rden, bb[j]);
        v = (v > 0.f) ? v : (__expf(v) - 1.f);
        o[j] = __float2bfloat16(v);
    }
    *(bf16x8*)(out + (size_t)n * GOUTD + lane * 8) = *(const bf16x8*)o;
}

// ---------------- GAT aggregate layer 2 + fused mean-pool: ONE BLOCK PER GRAPH (verified) ----------------
__global__ __launch_bounds__(256) void k_gat_agg_pool(
    const __hip_bfloat16* __restrict__ h, const float* __restrict__ asrc,
    const float* __restrict__ adst, const int* __restrict__ rowptr,
    const int* __restrict__ colI, const float* __restrict__ bias,
    const int* __restrict__ gstart, float* __restrict__ cfeat)
{
    __shared__ float red[4][512];
    int lane = threadIdx.x & 63;
    int wv = threadIdx.x >> 6;
    int g = blockIdx.x;
    int s = gstart[g], e = gstart[g + 1];
    int hh = lane >> 3;
    const float* bp = bias + lane * 8;
    float4 b0 = *(const float4*)bp, b1 = *(const float4*)(bp + 4);
    float bb[8] = {b0.x, b0.y, b0.z, b0.w, b1.x, b1.y, b1.z, b1.w};
    float psum[8] = {};
    for (int n = s + wv; n < e; n += 4) {
        int start = rowptr[n], end = rowptr[n + 1];
        float adst_h = adst[n * 8 + hh];
        float acc[8];
        float wsum;
        {
            float w = __expf(leaky02(asrc[n * 8 + hh] + adst_h));   // self loop
            wsum = w;
            bf16x8 v = *(const bf16x8*)(h + (size_t)n * GOUTD + lane * 8);
            #pragma unroll
            for (int j = 0; j < 8; ++j) acc[j] = w * (float)v[j];
        }
        int i = start;
        for (; i + 1 < end; i += 2) {
            int s0 = colI[i];
            int s1 = colI[i + 1];
            float w0 = __expf(leaky02(asrc[s0 * 8 + hh] + adst_h));
            float w1 = __expf(leaky02(asrc[s1 * 8 + hh] + adst_h));
            bf16x8 v0 = *(const bf16x8*)(h + (size_t)s0 * GOUTD + lane * 8);
            bf16x8 v1 = *(const bf16x8*)(h + (size_t)s1 * GOUTD + lane * 8);
            wsum += w0 + w1;
            #pragma unroll
            for (int j = 0; j < 8; ++j)
                acc[j] = fmaf(w0, (float)v0[j], fmaf(w1, (float)v1[j], acc[j]));
        }
        if (i < end) {
            int si = colI[i];
            float w = __expf(leaky02(asrc[si * 8 + hh] + adst_h));
            wsum += w;
            bf16x8 v = *(const bf16x8*)(h + (size_t)si * GOUTD + lane * 8);
            #pragma unroll
            for (int j = 0; j < 8; ++j) acc[j] = fmaf(w, (float)v[j], acc[j]);
        }
        float rden = 1.f / (wsum + 1e-16f);
        #pragma unroll
        for (int j = 0; j < 8; ++j) {
            float v = fmaf(acc[j], rden, bb[j]);
            v = (v > 0.f) ? v : (__expf(v) - 1.f);   // ELU
            psum[j] += v;
        }
    }
    #pragma unroll
    for (int j = 0; j < 8; ++j) red[wv][lane * 8 + j] = psum[j];
    __syncthreads();
    if (wv == 0) {
        float inv = 1.f / fmaxf((float)(e - s), 1.f);
        float* cp = cfeat + (size_t)g * 1024;
        #pragma unroll
        for (int j = 0; j < 8; ++j) {
            int c = lane * 8 + j;
            cp[c] = (red[0][c] + red[1][c] + red[2][c] + red[3][c]) * inv;
        }
    }
}

// ---------------- geno layer 1 as split-K GEMM: x_gen[2048,735] @ gW1[735,128] ----------------
__global__ __launch_bounds__(256) void k_geno1_sk(
    const float* __restrict__ A, const float* __restrict__ B, float* __restrict__ z1)
{
    __shared__ float As[32][34];
    __shared__ float Bs[32][68];
    int tid = threadIdx.x;
    int n0 = blockIdx.x * 64;            // 0 or 64 (N=128)
    int m0 = blockIdx.y * 32;
    int kbase = blockIdx.z * 192;
    int am = tid >> 3;
    int ak = (tid & 7) << 2;
    int bk = tid >> 4;
    int bc = (tid & 15) << 2;
    int tm = (tid >> 4) << 1;
    int tn = (tid & 15) << 2;
    float acc[2][4] = {};
    for (int kt = 0; kt < 192; kt += 32) {
        const float* ap = A + (size_t)(m0 + am) * 735 + kbase + kt + ak;
        int kg = kbase + kt + ak;
        As[ak][am]     = (kg     < 735) ? ap[0] : 0.f;
        As[ak + 1][am] = (kg + 1 < 735) ? ap[1] : 0.f;
        As[ak + 2][am] = (kg + 2 < 735) ? ap[2] : 0.f;
        As[ak + 3][am] = (kg + 3 < 735) ? ap[3] : 0.f;
        #pragma unroll
        for (int j = 0; j < 2; ++j) {
            int kr = j * 16 + bk;
            int kgb = kbase + kt + kr;
            float4 b4 = (kgb < 735) ? *(const float4*)(B + (size_t)kgb * 128 + n0 + bc)
                                    : make_float4(0.f, 0.f, 0.f, 0.f);
            *(float4*)&Bs[kr][bc] = b4;
        }
        __syncthreads();
        #pragma unroll
        for (int kk = 0; kk < 32; ++kk) {
            float2 a2 = *(const float2*)&As[kk][tm];
            float4 b4 = *(const float4*)&Bs[kk][tn];
            acc[0][0] = fmaf(a2.x, b4.x, acc[0][0]); acc[0][1] = fmaf(a2.x, b4.y, acc[0][1]);
            acc[0][2] = fmaf(a2.x, b4.z, acc[0][2]); acc[0][3] = fmaf(a2.x, b4.w, acc[0][3]);
            acc[1][0] = fmaf(a2.y, b4.x, acc[1][0]); acc[1][1] = fmaf(a2.y, b4.y, acc[1][1]);
            acc[1][2] = fmaf(a2.y, b4.z, acc[1][2]); acc[1][3] = fmaf(a2.y, b4.w, acc[1][3]);
        }
        __syncthreads();
    }
    #pragma unroll
    for (int i = 0; i < 2; ++i) {
        float* cp = z1 + (size_t)(m0 + tm + i) * 128 + n0 + tn;
        #pragma unroll
        for (int j = 0; j < 4; ++j) atomAddF(cp + j, acc[i][j]);
    }
}

// ---------------- geno layer 2 GEMM with fused BN+relu on A-load ----------------
__global__ __launch_bounds__(256) void k_geno2(
    const float* __restrict__ z1, const float* __restrict__ gW2,
    const float* __restrict__ gb1, const float* __restrict__ bn_mean,
    const float* __restrict__ bn_var, const float* __restrict__ bn_gamma,
    const float* __restrict__ bn_beta, const float* __restrict__ gb2,
    float* __restrict__ Cout)
{
    __shared__ float As[32][34];
    __shared__ float Bs[32][68];
    int tid = threadIdx.x;
    int n0 = blockIdx.x * 64;            // N=512 -> 8 n-blocks
    int m0 = blockIdx.y * 32;
    int am = tid >> 3;
    int ak = (tid & 7) << 2;
    int bk = tid >> 4;
    int bc = (tid & 15) << 2;
    int tm = (tid >> 4) << 1;
    int tn = (tid & 15) << 2;
    float acc[2][4] = {};
    for (int kt = 0; kt < 128; kt += 32) {
        int kg = kt + ak;
        float4 raw = *(const float4*)(z1 + (size_t)(m0 + am) * 128 + kg);
        float4 g1 = *(const float4*)(gb1 + kg);
        float4 mu = *(const float4*)(bn_mean + kg);
        float4 vr = *(const float4*)(bn_var + kg);
        float4 gm = *(const float4*)(bn_gamma + kg);
        float4 bt = *(const float4*)(bn_beta + kg);
        As[ak][am]     = fmaxf(fmaf(raw.x + g1.x - mu.x, rsqrtf(vr.x + 1e-5f) * gm.x, bt.x), 0.f);
        As[ak + 1][am] = fmaxf(fmaf(raw.y + g1.y - mu.y, rsqrtf(vr.y + 1e-5f) * gm.y, bt.y), 0.f);
        As[ak + 2][am] = fmaxf(fmaf(raw.z + g1.z - mu.z, rsqrtf(vr.z + 1e-5f) * gm.z, bt.z), 0.f);
        As[ak + 3][am] = fmaxf(fmaf(raw.w + g1.w - mu.w, rsqrtf(vr.w + 1e-5f) * gm.w, bt.w), 0.f);
        #pragma unroll
        for (int j = 0; j < 2; ++j) {
            int kr = j * 16 + bk;
            *(float4*)&Bs[kr][bc] = *(const float4*)(gW2 + (size_t)(kt + kr) * 512 + n0 + bc);
        }
        __syncthreads();
        #pragma unroll
        for (int kk = 0; kk < 32; ++kk) {
            float2 a2 = *(const float2*)&As[kk][tm];
            float4 b4 = *(const float4*)&Bs[kk][tn];
            acc[0][0] = fmaf(a2.x, b4.x, acc[0][0]); acc[0][1] = fmaf(a2.x, b4.y, acc[0][1]);
            acc[0][2] = fmaf(a2.x, b4.z, acc[0][2]); acc[0][3] = fmaf(a2.x, b4.w, acc[0][3]);
            acc[1][0] = fmaf(a2.y, b4.x, acc[1][0]); acc[1][1] = fmaf(a2.y, b4.y, acc[1][1]);
            acc[1][2] = fmaf(a2.y, b4.z, acc[1][2]); acc[1][3] = fmaf(a2.y, b4.w, acc[1][3]);
        }
        __syncthreads();
    }
    float4 bb = *(const float4*)(gb2 + n0 + tn);
    #pragma unroll
    for (int i = 0; i < 2; ++i) {
        float* cp = Cout + (size_t)(m0 + tm + i) * 1024 + n0 + tn;   // Cout pre-offset by 512
        *(float4*)cp = make_float4(fmaxf(acc[i][0] + bb.x, 0.f), fmaxf(acc[i][1] + bb.y, 0.f),
                                   fmaxf(acc[i][2] + bb.z, 0.f), fmaxf(acc[i][3] + bb.w, 0.f));
    }
}

// ---------------- fusion MLP layers 1-2: split-K fp32 GEMM, atomic accumulate ----------------
#define FBM 32
#define FBN 64
#define FKS 32

__global__ __launch_bounds__(256) void k_fgemm_sk(
    const float* __restrict__ A, const float* __restrict__ B,
    float* __restrict__ C, int N, int K, int KS, int reluA)
{
    __shared__ float As[FKS][FBM + 2];   // [k][m]
    __shared__ float Bs[FKS][FBN + 4];   // [k][n]
    int tid = threadIdx.x;
    int n0 = blockIdx.x * FBN;
    int m0 = blockIdx.y * FBM;
    int kbase = blockIdx.z * KS;
    int am = tid >> 3;
    int ak = (tid & 7) << 2;
    int bk = tid >> 4;
    int bc = (tid & 15) << 2;
    int tm = (tid >> 4) << 1;
    int tn = (tid & 15) << 2;
    float acc[2][4] = {};
    for (int kt = 0; kt < KS; kt += FKS) {
        float4 a4 = *(const float4*)(A + (size_t)(m0 + am) * K + kbase + kt + ak);
        if (reluA) {
            a4.x = fmaxf(a4.x, 0.f); a4.y = fmaxf(a4.y, 0.f);
            a4.z = fmaxf(a4.z, 0.f); a4.w = fmaxf(a4.w, 0.f);
        }
        As[ak][am] = a4.x; As[ak + 1][am] = a4.y;
        As[ak + 2][am] = a4.z; As[ak + 3][am] = a4.w;
        #pragma unroll
        for (int j = 0; j < 2; ++j) {
            int kr = j * 16 + bk;
            *(float4*)&Bs[kr][bc] = *(const float4*)(B + (size_t)(kbase + kt + kr) * N + n0 + bc);
        }
        __syncthreads();
        #pragma unroll
        for (int kk = 0; kk < FKS; ++kk) {
            float2 a2 = *(const float2*)&As[kk][tm];
            float4 b4 = *(const float4*)&Bs[kk][tn];
            acc[0][0] = fmaf(a2.x, b4.x, acc[0][0]); acc[0][1] = fmaf(a2.x, b4.y, acc[0][1]);
            acc[0][2] = fmaf(a2.x, b4.z, acc[0][2]); acc[0][3] = fmaf(a2.x, b4.w, acc[0][3]);
            acc[1][0] = fmaf(a2.y, b4.x, acc[1][0]); acc[1][1] = fmaf(a2.y, b4.y, acc[1][1]);
            acc[1][2] = fmaf(a2.y, b4.z, acc[1][2]); acc[1][3] = fmaf(a2.y, b4.w, acc[1][3]);
        }
        __syncthreads();
    }
    #pragma unroll
    for (int i = 0; i < 2; ++i) {
        float* cp = C + (size_t)(m0 + tm + i) * N + n0 + tn;
        #pragma unroll
        for (int j = 0; j < 4; ++j) atomAddF(cp + j, acc[i][j]);
    }
}

// ---------------- fusion output layer (relu on load of t2) ----------------
__global__ __launch_bounds__(256) void k_fout(
    const float* __restrict__ t2, const float* __restrict__ fW3,
    const float* __restrict__ fb3, float* __restrict__ out)
{
    int lane = threadIdx.x & 63;
    int row = blockIdx.x * 4 + (threadIdx.x >> 6);
    const float* tp = t2 + (size_t)row * 128;
    float p = fmaxf(tp[lane], 0.f) * fW3[lane] + fmaxf(tp[lane + 64], 0.f) * fW3[lane + 64];
    #pragma unroll
    for (int d = 1; d < 64; d <<= 1) p += __shfl_xor(p, d);
    if (lane == 0) out[row] = p + fb3[0];
}

extern "C" void kernel_launch(void* const* d_in, const int* in_sizes, int n_in,
                              void* d_out, int out_size, void* d_ws, size_t ws_size,
                              hipStream_t stream) {
    const float* x        = (const float*)d_in[0];
    const int*   ei       = (const int*)d_in[1];
    const int*   batch    = (const int*)d_in[2];
    const float* x_gen    = (const float*)d_in[3];
    const float* W1       = (const float*)d_in[4];
    const float* att_src1 = (const float*)d_in[5];
    const float* att_dst1 = (const float*)d_in[6];
    const float* bias1    = (const float*)d_in[7];
    const float* W2       = (const float*)d_in[8];
    const float* att_src2 = (const float*)d_in[9];
    const float* att_dst2 = (const float*)d_in[10];
    const float* bias2    = (const float*)d_in[11];
    const float* gW1      = (const float*)d_in[12];
    const float* gb1      = (const float*)d_in[13];
    const float* bn_gamma = (const float*)d_in[14];
    const float* bn_beta  = (const float*)d_in[15];
    const float* bn_mean  = (const float*)d_in[16];
    const float* bn_var   = (const float*)d_in[17];
    const float* gW2      = (const float*)d_in[18];
    const float* gb2      = (const float*)d_in[19];
    const float* fW1      = (const float*)d_in[20];
    const float* fb1      = (const float*)d_in[21];
    const float* fW2      = (const float*)d_in[22];
    const float* fb2      = (const float*)d_in[23];
    const float* fW3      = (const float*)d_in[24];
    const float* fb3      = (const float*)d_in[25];
    float* out = (float*)d_out;

    const int* srcv = ei;
    const int* dstv = ei + NE;

    char* w = (char*)d_ws;
    size_t off = 0;
    auto take = [&](size_t bytes) -> void* {
        void* p = w + off;
        off += (bytes + 255) & ~(size_t)255;
        return p;
    };
    __hip_bfloat16* hbuf = (__hip_bfloat16*)take((size_t)NN * GOUTD * 2);
    __hip_bfloat16* abuf = (__hip_bfloat16*)take((size_t)NN * GOUTD * 2);
    __hip_bfloat16* xb   = (__hip_bfloat16*)take((size_t)NN * 128 * 2);   // 16 MB
    __hip_bfloat16* w1t  = (__hip_bfloat16*)take((size_t)512 * 128 * 2);
    __hip_bfloat16* w2t  = (__hip_bfloat16*)take((size_t)512 * 512 * 2);
    float* asrc   = (float*)take((size_t)NN * 8 * 4);
    float* adst   = (float*)take((size_t)NN * 8 * 4);
    int*   rowptr = (int*)take((size_t)(NN + 1) * 4);
    int*   colI   = (int*)take((size_t)NE * 4);
    int*   deg    = (int*)take((size_t)NN * 4);
    int*   fill   = (int*)take((size_t)NN * 4);
    int*   bsum   = (int*)take(256 * 4);
    int*   gstart = (int*)take((NB + 1) * 4);
    float* cbuf = (float*)xb;                       // [2048, 1024]  8 MB (aliases xb; xb dead after gemm1)
    float* z1   = cbuf + (size_t)2048 * 1024;       // [2048, 128]   1 MB (zeroed by gemm2 tail)
    float* t1   = z1 + (size_t)2048 * 128;          // [2048, 256]   2 MB
    float* t2   = t1 + (size_t)2048 * 256;          // [2048, 128]   1 MB

    // ---- conversions + prep (merged), then CSR build ----
    k_cvt_prep<<<17920, 256, 0, stream>>>(x, W1, W2, xb, w1t, w2t, deg, fill, batch, gstart);
    k_hist<<<NE / 256, 256, 0, stream>>>(dstv, deg);
    k_scan_block<<<256, 256, 0, stream>>>(deg, rowptr, bsum);
    k_scan_add2<<<256, 256, 0, stream>>>(rowptr, bsum);

    // ---- GAT layer 1 GEMM (128x128, K=128 is epilogue-bound -> 2048 blocks)
    //      + CSR scatter folded into the same launch (blocks 2048..3071) ----
    k_mfma_gemm1<<<3072, 256, 0, stream>>>(xb, w1t, hbuf, 128, att_src1, att_dst1, asrc, adst,
                                           srcv, dstv, rowptr, fill, colI);
    k_gat_agg<<<NN / 4, 256, 0, stream>>>(hbuf, asrc, adst, rowptr, colI, bias1, abuf);

    // ---- GAT layer 2 GEMM (128x256; tail inits t1/t2, zeroes z1; xb dead after gemm1) ----
    k_mfma_gemm<<<1024, 512, 0, stream>>>(abuf, w2t, hbuf, 512, att_src2, att_dst2, asrc, adst,
                                          t1, t2, fb1, fb2, z1);

    // ---- agg_pool (one block per graph) ----
    k_gat_agg_pool<<<NB, 256, 0, stream>>>(hbuf, asrc, adst, rowptr, colI, bias2,
                                           gstart, cbuf);

    // ---- genomic encoder as 2 tiled GEMMs ----
    k_geno1_sk<<<dim3(2, 64, 4), 256, 0, stream>>>(x_gen, gW1, z1);
    k_geno2<<<dim3(8, 64), 256, 0, stream>>>(z1, gW2, gb1, bn_mean, bn_var, bn_gamma,
                                             bn_beta, gb2, cbuf + 512);

    // ---- fusion MLP: 1024 -> 256 -> 128 -> 1 (split-K fp32, atomic accumulate) ----
    k_fgemm_sk<<<dim3(4, 64, 4), 256, 0, stream>>>(cbuf, fW1, t1, 256, 1024, 256, 0);
    k_fgemm_sk<<<dim3(2, 64, 4), 256, 0, stream>>>(t1, fW2, t2, 128, 256, 64, 1);
    k_fout<<<NB / 4, 256, 0, stream>>>(t2, fW3, fb3, out);
}

// Round 12
// 407.968 us; speedup vs baseline: 1.1031x; 1.0627x over previous
//
#include <hip/hip_runtime.h>
#include <hip/hip_bf16.h>
#include <cstdint>
#include <cstddef>

#define NN 65536
#define NE 262144
#define NB 2048
#define FIN 78
#define GOUTD 512

typedef __bf16 bf16x8 __attribute__((ext_vector_type(8)));
typedef float f32x4 __attribute__((ext_vector_type(4)));

__device__ __forceinline__ float leaky02(float x) { return x > 0.f ? x : 0.2f * x; }
__device__ __forceinline__ void atomAddF(float* p, float v) { unsafeAtomicAdd(p, v); }

// ---------------- CSR build ----------------
__global__ void k_hist(const int* __restrict__ dst, int* __restrict__ deg) {
    int i = blockIdx.x * 256 + threadIdx.x;
    if (i < NE) atomicAdd(&deg[dst[i]], 1);
}

__global__ void k_scan_block(const int* __restrict__ deg, int* __restrict__ ex, int* __restrict__ bsum) {
    __shared__ int s[256];
    int t = threadIdx.x; int g = blockIdx.x * 256 + t;
    int v = deg[g];
    s[t] = v; __syncthreads();
    for (int d = 1; d < 256; d <<= 1) {
        int x = (t >= d) ? s[t - d] : 0;
        __syncthreads();
        s[t] += x;
        __syncthreads();
    }
    ex[g] = s[t] - v;
    if (t == 255) bsum[blockIdx.x] = s[t];
}

// merged scan_bsum + scan_add
__global__ void k_scan_add2(int* __restrict__ rowptr, const int* __restrict__ bsum) {
    __shared__ int s[256];
    int t = threadIdx.x;
    int v = bsum[t];
    s[t] = v; __syncthreads();
    for (int d = 1; d < 256; d <<= 1) {
        int x = (t >= d) ? s[t - d] : 0;
        __syncthreads();
        s[t] += x;
        __syncthreads();
    }
    int prefix = (blockIdx.x == 0) ? 0 : s[blockIdx.x - 1];
    int i = blockIdx.x * 256 + t;
    rowptr[i] += prefix;
    if (i == 0) rowptr[NN] = NE;
}

// ---------------- merged conversions + prep: x->xb (float4), W1^T, W2^T, deg/fill zero, gstart ----------------
// Blocks: [0,8192) x-cvt (4 floats/thread), [8192,8448) w1t, [8448,9472) w2t, [9472,9728) prep.
__global__ void k_cvt_prep(const float* __restrict__ x, const float* __restrict__ W1,
                           const float* __restrict__ W2, __hip_bfloat16* __restrict__ xb,
                           __hip_bfloat16* __restrict__ w1t, __hip_bfloat16* __restrict__ w2t,
                           int* __restrict__ deg, int* __restrict__ fill,
                           const int* __restrict__ batch, int* __restrict__ gstart)
{
    int blk = blockIdx.x;
    if (blk < 8192) {
        int i = blk * 256 + threadIdx.x;     // over NN*32 quads
        int row = i >> 5;
        int c = (i & 31) << 2;
        float4 v;
        if (c + 3 < FIN) {                   // c <= 74: full quad in-bounds
            v = *(const float4*)(x + (size_t)row * FIN + c);
        } else if (c < FIN) {                // c == 76: last 2 valid
            float2 v2 = *(const float2*)(x + (size_t)row * FIN + c);
            v = make_float4(v2.x, v2.y, 0.f, 0.f);
        } else {
            v = make_float4(0.f, 0.f, 0.f, 0.f);
        }
        __hip_bfloat16 o[4] __attribute__((aligned(8)));
        o[0] = __float2bfloat16(v.x);
        o[1] = __float2bfloat16(v.y);
        o[2] = __float2bfloat16(v.z);
        o[3] = __float2bfloat16(v.w);
        *(uint2*)&xb[(size_t)row * 128 + c] = *(const uint2*)o;
    } else if (blk < 8448) {
        int i = (blk - 8192) * 256 + threadIdx.x;   // over 512*128
        int n = i >> 7, k = i & 127;
        w1t[i] = __float2bfloat16(k < FIN ? W1[(size_t)k * 512 + n] : 0.f);
    } else if (blk < 9472) {
        int i = (blk - 8448) * 256 + threadIdx.x;   // over 512*512
        int n = i >> 9, k = i & 511;
        w2t[i] = __float2bfloat16(W2[(size_t)k * 512 + n]);
    } else {
        int i = (blk - 9472) * 256 + threadIdx.x;   // prep over NN
        if (i < NN) {
            deg[i] = 0; fill[i] = 0;
            int cur = batch[i];
            int prev = (i == 0) ? -1 : batch[i - 1];
            for (int g = prev + 1; g <= cur; ++g) gstart[g] = i;
            if (i == NN - 1) {
                for (int g = cur + 1; g <= NB; ++g) gstart[g] = NN;
            }
        }
    }
}

// ---------------- gemm1: bf16 MFMA GEMM (128x128, 256thr) + attn logits + folded scatter ----------------
__global__ __launch_bounds__(256) void k_mfma_gemm1(
    const __hip_bfloat16* __restrict__ A, const __hip_bfloat16* __restrict__ BT,
    __hip_bfloat16* __restrict__ C, int K,
    const float* __restrict__ att_src, const float* __restrict__ att_dst,
    float* __restrict__ a_src, float* __restrict__ a_dst,
    const int* __restrict__ srcv, const int* __restrict__ dstv,
    const int* __restrict__ rowptr, int* __restrict__ fill, int* __restrict__ colI)
{
    if (blockIdx.x >= 2048) {            // ---- scatter branch ----
        int i = (blockIdx.x - 2048) * 256 + threadIdx.x;
        if (i < NE) {
            int d = dstv[i];
            int pos = rowptr[d] + atomicAdd(&fill[d], 1);
            colI[pos] = srcv[i];
        }
        return;
    }
    __shared__ __hip_bfloat16 smem[128 * 128];          // 32 KB
    __hip_bfloat16* As = smem;
    __hip_bfloat16* Bs = smem + 128 * 64;
    int tid = threadIdx.x;
    int lane = tid & 63;
    int wave = tid >> 6;
    int id = blockIdx.x;
    int m0 = (((id >> 5) << 3) + (id & 7)) * 128;
    int n0 = ((id >> 3) & 3) * 128;
    int wm = (wave >> 1) * 64;
    int wn = (wave & 1) * 64;
    f32x4 acc[4][4] = {};

    int swz = lane & 7;

    for (int k0 = 0; k0 < K; k0 += 64) {
        #pragma unroll
        for (int c = 0; c < 4; ++c) {
            int off = c * 4096 + tid * 16;
            int r = off >> 7;
            int c16 = (off >> 4) & 7;
            int c16s = c16 ^ (r & 7);
            __builtin_amdgcn_global_load_lds(
                (const __attribute__((address_space(1))) void*)(A + (size_t)(m0 + r) * K + k0 + c16s * 8),
                (__attribute__((address_space(3))) void*)((char*)As + off), 16, 0, 0);
            __builtin_amdgcn_global_load_lds(
                (const __attribute__((address_space(1))) void*)(BT + (size_t)(n0 + r) * K + k0 + c16s * 8),
                (__attribute__((address_space(3))) void*)((char*)Bs + off), 16, 0, 0);
        }
        __syncthreads();
        #pragma unroll
        for (int kk = 0; kk < 64; kk += 32) {
            int c16r = (kk >> 3) + (lane >> 4);
            bf16x8 af[4], bfr[4];
            #pragma unroll
            for (int t = 0; t < 4; ++t) {
                int ra = wm + t * 16 + (lane & 15);
                int rb = wn + t * 16 + (lane & 15);
                af[t]  = *(const bf16x8*)((char*)As + ra * 128 + ((c16r ^ swz) << 4));
                bfr[t] = *(const bf16x8*)((char*)Bs + rb * 128 + ((c16r ^ swz) << 4));
            }
            #pragma unroll
            for (int i = 0; i < 4; ++i)
                #pragma unroll
                for (int j = 0; j < 4; ++j)
                    acc[i][j] = __builtin_amdgcn_mfma_f32_16x16x32_bf16(af[i], bfr[j], acc[i][j], 0, 0, 0);
        }
        __syncthreads();
    }

    int rowb = wm + ((lane >> 4) << 2);
    int colb = wn + (lane & 15);
    #pragma unroll
    for (int i = 0; i < 4; ++i) {
        #pragma unroll
        for (int j = 0; j < 4; ++j) {
            int cc = colb + j * 16;
            #pragma unroll
            for (int r = 0; r < 4; ++r) {
                int rr = rowb + i * 16 + r;
                int word = (cc >> 1) ^ (((rr >> 2) & 7) << 3);
                smem[rr * 128 + word * 2 + (cc & 1)] = __float2bfloat16(acc[i][j][r]);
            }
        }
    }
    __syncthreads();
    #pragma unroll
    for (int cc2 = 0; cc2 < 8; ++cc2) {
        int p = cc2 * 256 + tid;
        int rr = p >> 4;
        int c16 = p & 15;
        int x = ((rr >> 2) & 7) << 3;
        bf16x8 v = *(const bf16x8*)((char*)smem + rr * 256 + ((((c16 << 2) ^ x)) << 2));
        *(bf16x8*)(C + (size_t)(m0 + rr) * 512 + n0 + c16 * 8) = v;
        const float* sp = att_src + n0 + c16 * 8;
        const float* dp = att_dst + n0 + c16 * 8;
        float4 s0 = *(const float4*)sp, s1 = *(const float4*)(sp + 4);
        float4 d0 = *(const float4*)dp, d1 = *(const float4*)(dp + 4);
        float sv[8] = {s0.x, s0.y, s0.z, s0.w, s1.x, s1.y, s1.z, s1.w};
        float dv[8] = {d0.x, d0.y, d0.z, d0.w, d1.x, d1.y, d1.z, d1.w};
        float ps = 0.f, pd = 0.f;
        #pragma unroll
        for (int k = 0; k < 8; ++k) {
            float f = (float)v[k];
            ps = fmaf(f, sv[k], ps);
            pd = fmaf(f, dv[k], pd);
        }
        #pragma unroll
        for (int d = 1; d < 8; d <<= 1) {
            ps += __shfl_xor(ps, d);
            pd += __shfl_xor(pd, d);
        }
        if ((c16 & 7) == 0) {
            int head = (n0 >> 6) + (c16 >> 3);
            a_src[(size_t)(m0 + rr) * 8 + head] = ps;
            a_dst[(size_t)(m0 + rr) * 8 + head] = pd;
        }
    }
}

// ---------------- gemm2: bf16 MFMA GEMM (128x256 tile, 8 waves) + attn + init tail ----------------
__global__ __launch_bounds__(512) void k_mfma_gemm(
    const __hip_bfloat16* __restrict__ A, const __hip_bfloat16* __restrict__ BT,
    __hip_bfloat16* __restrict__ C, int K,
    const float* __restrict__ att_src, const float* __restrict__ att_dst,
    float* __restrict__ a_src, float* __restrict__ a_dst,
    float* __restrict__ t1, float* __restrict__ t2,
    const float* __restrict__ fb1, const float* __restrict__ fb2,
    float* __restrict__ z1)
{
    __shared__ __hip_bfloat16 smem[128 * 64 + 256 * 64];   // A 16KB + B 32KB = 48KB
    __hip_bfloat16* As = smem;
    __hip_bfloat16* Bs = smem + 128 * 64;
    int tid = threadIdx.x;
    int lane = tid & 63;
    int wave = tid >> 6;          // 0..7
    int wr = wave >> 2;           // 0..1 (m)
    int wc = wave & 3;            // 0..3 (n)
    int id = blockIdx.x;
    int m0 = (((id >> 4) << 3) + (id & 7)) * 128;
    int n0 = ((id >> 3) & 1) * 256;
    int wm = wr * 64;
    int wn = wc * 64;
    f32x4 acc[4][4] = {};

    int swz = lane & 7;

    for (int k0 = 0; k0 < K; k0 += 64) {
        #pragma unroll
        for (int c = 0; c < 2; ++c) {          // A: 16KB, 2 rounds
            int off = c * 8192 + tid * 16;
            int r = off >> 7;
            int c16 = (off >> 4) & 7;
            int c16s = c16 ^ (r & 7);
            __builtin_amdgcn_global_load_lds(
                (const __attribute__((address_space(1))) void*)(A + (size_t)(m0 + r) * K + k0 + c16s * 8),
                (__attribute__((address_space(3))) void*)((char*)As + off), 16, 0, 0);
        }
        #pragma unroll
        for (int c = 0; c < 4; ++c) {          // B: 32KB, 4 rounds
            int off = c * 8192 + tid * 16;
            int r = off >> 7;                  // 0..255
            int c16 = (off >> 4) & 7;
            int c16s = c16 ^ (r & 7);
            __builtin_amdgcn_global_load_lds(
                (const __attribute__((address_space(1))) void*)(BT + (size_t)(n0 + r) * K + k0 + c16s * 8),
                (__attribute__((address_space(3))) void*)((char*)Bs + off), 16, 0, 0);
        }
        __syncthreads();
        #pragma unroll
        for (int kk = 0; kk < 64; kk += 32) {
            int c16r = (kk >> 3) + (lane >> 4);
            bf16x8 af[4], bfr[4];
            #pragma unroll
            for (int t = 0; t < 4; ++t) {
                int ra = wm + t * 16 + (lane & 15);
                int rb = wn + t * 16 + (lane & 15);
                af[t]  = *(const bf16x8*)((char*)As + ra * 128 + ((c16r ^ swz) << 4));
                bfr[t] = *(const bf16x8*)((char*)Bs + rb * 128 + ((c16r ^ swz) << 4));
            }
            #pragma unroll
            for (int i = 0; i < 4; ++i)
                #pragma unroll
                for (int j = 0; j < 4; ++j)
                    acc[i][j] = __builtin_amdgcn_mfma_f32_16x16x32_bf16(af[i], bfr[j], acc[i][j], 0, 0, 0);
        }
        __syncthreads();
    }

    // ---- epilogue: two 128-col passes ----
    #pragma unroll
    for (int p = 0; p < 2; ++p) {
        if ((wc >> 1) == p) {
            int rowb = wm + ((lane >> 4) << 2);
            int colb = (wc & 1) * 64 + (lane & 15);
            #pragma unroll
            for (int i = 0; i < 4; ++i) {
                #pragma unroll
                for (int j = 0; j < 4; ++j) {
                    int cc = colb + j * 16;
                    #pragma unroll
                    for (int r = 0; r < 4; ++r) {
                        int rr = rowb + i * 16 + r;
                        int word = (cc >> 1) ^ (((rr >> 2) & 7) << 3);
                        smem[rr * 128 + word * 2 + (cc & 1)] = __float2bfloat16(acc[i][j][r]);
                    }
                }
            }
        }
        __syncthreads();
        int cb = n0 + p * 128;
        #pragma unroll
        for (int cc2 = 0; cc2 < 4; ++cc2) {
            int pi = cc2 * 512 + tid;
            int rr = pi >> 4;
            int c16 = pi & 15;
            int x = ((rr >> 2) & 7) << 3;
            bf16x8 v = *(const bf16x8*)((char*)smem + rr * 256 + ((((c16 << 2) ^ x)) << 2));
            *(bf16x8*)(C + (size_t)(m0 + rr) * 512 + cb + c16 * 8) = v;
            const float* sp = att_src + cb + c16 * 8;
            const float* dp = att_dst + cb + c16 * 8;
            float4 s0 = *(const float4*)sp, s1 = *(const float4*)(sp + 4);
            float4 d0 = *(const float4*)dp, d1 = *(const float4*)(dp + 4);
            float sv[8] = {s0.x, s0.y, s0.z, s0.w, s1.x, s1.y, s1.z, s1.w};
            float dv[8] = {d0.x, d0.y, d0.z, d0.w, d1.x, d1.y, d1.z, d1.w};
            float ps = 0.f, pd = 0.f;
            #pragma unroll
            for (int k = 0; k < 8; ++k) {
                float f = (float)v[k];
                ps = fmaf(f, sv[k], ps);
                pd = fmaf(f, dv[k], pd);
            }
            #pragma unroll
            for (int d = 1; d < 8; d <<= 1) {
                ps += __shfl_xor(ps, d);
                pd += __shfl_xor(pd, d);
            }
            if ((c16 & 7) == 0) {
                int head = (cb >> 6) + (c16 >> 3);
                a_src[(size_t)(m0 + rr) * 8 + head] = ps;
                a_dst[(size_t)(m0 + rr) * 8 + head] = pd;
            }
        }
        __syncthreads();
    }

    // ---- tail: rows 2id, 2id+1: t1=fb1, t2=fb2, z1=0 ----
    if (t1) {
        if (tid < 128) {
            int r = 2 * id + (tid >> 6), e = tid & 63;
            *(float4*)(t1 + (size_t)r * 256 + e * 4) = *(const float4*)(fb1 + e * 4);
        } else if (tid < 192) {
            int q = tid - 128, r = 2 * id + (q >> 5), e = q & 31;
            *(float4*)(t2 + (size_t)r * 128 + e * 4) = *(const float4*)(fb2 + e * 4);
        } else if (tid < 256) {
            int q = tid - 192, r = 2 * id + (q >> 5), e = q & 31;
            *(float4*)(z1 + (size_t)r * 128 + e * 4) = make_float4(0.f, 0.f, 0.f, 0.f);
        }
    }
}

// ---------------- GAT aggregate (layer 1): single-pass, 2-edge pipeline (verified) ----------------
__global__ __launch_bounds__(256) void k_gat_agg(
    const __hip_bfloat16* __restrict__ h, const float* __restrict__ asrc,
    const float* __restrict__ adst, const int* __restrict__ rowptr,
    const int* __restrict__ colI, const float* __restrict__ bias,
    __hip_bfloat16* __restrict__ out)
{
    int lane = threadIdx.x & 63;
    int n = blockIdx.x * 4 + (threadIdx.x >> 6);
    int start = rowptr[n], end = rowptr[n + 1];
    int hh = lane >> 3;
    float adst_h = adst[n * 8 + hh];
    float acc[8];
    float wsum;
    {
        float w = __expf(leaky02(asrc[n * 8 + hh] + adst_h));   // self loop
        wsum = w;
        bf16x8 v = *(const bf16x8*)(h + (size_t)n * GOUTD + lane * 8);
        #pragma unroll
        for (int j = 0; j < 8; ++j) acc[j] = w * (float)v[j];
    }
    int i = start;
    for (; i + 1 < end; i += 2) {
        int s0 = colI[i];
        int s1 = colI[i + 1];
        float w0 = __expf(leaky02(asrc[s0 * 8 + hh] + adst_h));
        float w1 = __expf(leaky02(asrc[s1 * 8 + hh] + adst_h));
        bf16x8 v0 = *(const bf16x8*)(h + (size_t)s0 * GOUTD + lane * 8);
        bf16x8 v1 = *(const bf16x8*)(h + (size_t)s1 * GOUTD + lane * 8);
        wsum += w0 + w1;
        #pragma unroll
        for (int j = 0; j < 8; ++j)
            acc[j] = fmaf(w0, (float)v0[j], fmaf(w1, (float)v1[j], acc[j]));
    }
    if (i < end) {
        int s = colI[i];
        float w = __expf(leaky02(asrc[s * 8 + hh] + adst_h));
        wsum += w;
        bf16x8 v = *(const bf16x8*)(h + (size_t)s * GOUTD + lane * 8);
        #pragma unroll
        for (int j = 0; j < 8; ++j) acc[j] = fmaf(w, (float)v[j], acc[j]);
    }
    float rden = 1.f / (wsum + 1e-16f);
    const float* bp = bias + lane * 8;
    float4 b0 = *(const float4*)bp, b1 = *(const float4*)(bp + 4);
    float bb[8] = {b0.x, b0.y, b0.z, b0.w, b1.x, b1.y, b1.z, b1.w};
    __hip_bfloat16 o[8] __attribute__((aligned(16)));
    #pragma unroll
    for (int j = 0; j < 8; ++j) {
        float v = fmaf(acc[j], rden, bb[j]);
        v = (v > 0.f) ? v : (__expf(v) - 1.f);
        o[j] = __float2bfloat16(v);
    }
    *(bf16x8*)(out + (size_t)n * GOUTD + lane * 8) = *(const bf16x8*)o;
}

// ---------------- aggpool (blocks [0,2048)) + geno1 split-K GEMM (blocks [2048,2560)) ----------------
// Both depend only on gemm2 (z1 zeroed in its tail) and write disjoint buffers.
// geno1 blocks backfill aggpool's variable-duration drain tail; saves a launch.
__global__ __launch_bounds__(256) void k_aggpool_geno1(
    const __hip_bfloat16* __restrict__ h, const float* __restrict__ asrc,
    const float* __restrict__ adst, const int* __restrict__ rowptr,
    const int* __restrict__ colI, const float* __restrict__ bias,
    const int* __restrict__ gstart, float* __restrict__ cfeat,
    const float* __restrict__ xg, const float* __restrict__ gW1, float* __restrict__ z1)
{
    __shared__ char smraw[13056];        // union: aggpool red[4][512]=8KB | geno1 As+Bs=12.75KB
    int bid = blockIdx.x;
    int tid = threadIdx.x;
    if (bid < NB) {
        // ================= aggpool path (R7-verified math) =================
        float (*red)[512] = (float (*)[512])smraw;
        int lane = tid & 63;
        int wv = tid >> 6;
        int g = bid;
        int s = gstart[g], e = gstart[g + 1];
        int hh = lane >> 3;
        const float* bp = bias + lane * 8;
        float4 b0 = *(const float4*)bp, b1 = *(const float4*)(bp + 4);
        float bb[8] = {b0.x, b0.y, b0.z, b0.w, b1.x, b1.y, b1.z, b1.w};
        float psum[8] = {};
        for (int n = s + wv; n < e; n += 4) {
            int start = rowptr[n], end = rowptr[n + 1];
            float adst_h = adst[n * 8 + hh];
            float acc[8];
            float wsum;
            {
                float w = __expf(leaky02(asrc[n * 8 + hh] + adst_h));   // self loop
                wsum = w;
                bf16x8 v = *(const bf16x8*)(h + (size_t)n * GOUTD + lane * 8);
                #pragma unroll
                for (int j = 0; j < 8; ++j) acc[j] = w * (float)v[j];
            }
            int i = start;
            for (; i + 1 < end; i += 2) {
                int s0 = colI[i];
                int s1 = colI[i + 1];
                float w0 = __expf(leaky02(asrc[s0 * 8 + hh] + adst_h));
                float w1 = __expf(leaky02(asrc[s1 * 8 + hh] + adst_h));
                bf16x8 v0 = *(const bf16x8*)(h + (size_t)s0 * GOUTD + lane * 8);
                bf16x8 v1 = *(const bf16x8*)(h + (size_t)s1 * GOUTD + lane * 8);
                wsum += w0 + w1;
                #pragma unroll
                for (int j = 0; j < 8; ++j)
                    acc[j] = fmaf(w0, (float)v0[j], fmaf(w1, (float)v1[j], acc[j]));
            }
            if (i < end) {
                int si = colI[i];
                float w = __expf(leaky02(asrc[si * 8 + hh] + adst_h));
                wsum += w;
                bf16x8 v = *(const bf16x8*)(h + (size_t)si * GOUTD + lane * 8);
                #pragma unroll
                for (int j = 0; j < 8; ++j) acc[j] = fmaf(w, (float)v[j], acc[j]);
            }
            float rden = 1.f / (wsum + 1e-16f);
            #pragma unroll
            for (int j = 0; j < 8; ++j) {
                float v = fmaf(acc[j], rden, bb[j]);
                v = (v > 0.f) ? v : (__expf(v) - 1.f);   // ELU
                psum[j] += v;
            }
        }
        #pragma unroll
        for (int j = 0; j < 8; ++j) red[wv][lane * 8 + j] = psum[j];
        __syncthreads();
        if (wv == 0) {
            float inv = 1.f / fmaxf((float)(e - s), 1.f);
            float* cp = cfeat + (size_t)g * 1024;
            #pragma unroll
            for (int j = 0; j < 8; ++j) {
                int c = lane * 8 + j;
                cp[c] = (red[0][c] + red[1][c] + red[2][c] + red[3][c]) * inv;
            }
        }
    } else {
        // ================= geno1 split-K path (flattened dim3(2,64,4)) =================
        float (*As)[34] = (float (*)[34])smraw;                 // [32][34] = 4352B
        float (*Bs)[68] = (float (*)[68])(smraw + 4352);        // [32][68] = 8704B
        int b = bid - NB;
        int n0 = (b & 1) * 64;
        int m0 = ((b >> 1) & 63) * 32;
        int kbase = (b >> 7) * 192;
        int am = tid >> 3;
        int ak = (tid & 7) << 2;
        int bk = tid >> 4;
        int bc = (tid & 15) << 2;
        int tm = (tid >> 4) << 1;
        int tn = (tid & 15) << 2;
        float acc[2][4] = {};
        for (int kt = 0; kt < 192; kt += 32) {
            const float* ap = xg + (size_t)(m0 + am) * 735 + kbase + kt + ak;
            int kg = kbase + kt + ak;
            As[ak][am]     = (kg     < 735) ? ap[0] : 0.f;
            As[ak + 1][am] = (kg + 1 < 735) ? ap[1] : 0.f;
            As[ak + 2][am] = (kg + 2 < 735) ? ap[2] : 0.f;
            As[ak + 3][am] = (kg + 3 < 735) ? ap[3] : 0.f;
            #pragma unroll
            for (int j = 0; j < 2; ++j) {
                int kr = j * 16 + bk;
                int kgb = kbase + kt + kr;
                float4 b4 = (kgb < 735) ? *(const float4*)(gW1 + (size_t)kgb * 128 + n0 + bc)
                                        : make_float4(0.f, 0.f, 0.f, 0.f);
                *(float4*)&Bs[kr][bc] = b4;
            }
            __syncthreads();
            #pragma unroll
            for (int kk = 0; kk < 32; ++kk) {
                float2 a2 = *(const float2*)&As[kk][tm];
                float4 b4 = *(const float4*)&Bs[kk][tn];
                acc[0][0] = fmaf(a2.x, b4.x, acc[0][0]); acc[0][1] = fmaf(a2.x, b4.y, acc[0][1]);
                acc[0][2] = fmaf(a2.x, b4.z, acc[0][2]); acc[0][3] = fmaf(a2.x, b4.w, acc[0][3]);
                acc[1][0] = fmaf(a2.y, b4.x, acc[1][0]); acc[1][1] = fmaf(a2.y, b4.y, acc[1][1]);
                acc[1][2] = fmaf(a2.y, b4.z, acc[1][2]); acc[1][3] = fmaf(a2.y, b4.w, acc[1][3]);
            }
            __syncthreads();
        }
        #pragma unroll
        for (int i = 0; i < 2; ++i) {
            float* cp = z1 + (size_t)(m0 + tm + i) * 128 + n0 + tn;
            #pragma unroll
            for (int j = 0; j < 4; ++j) atomAddF(cp + j, acc[i][j]);
        }
    }
}

// ---------------- geno layer 2 GEMM with fused BN+relu on A-load ----------------
__global__ __launch_bounds__(256) void k_geno2(
    const float* __restrict__ z1, const float* __restrict__ gW2,
    const float* __restrict__ gb1, const float* __restrict__ bn_mean,
    const float* __restrict__ bn_var, const float* __restrict__ bn_gamma,
    const float* __restrict__ bn_beta, const float* __restrict__ gb2,
    float* __restrict__ Cout)
{
    __shared__ float As[32][34];
    __shared__ float Bs[32][68];
    int tid = threadIdx.x;
    int n0 = blockIdx.x * 64;            // N=512 -> 8 n-blocks
    int m0 = blockIdx.y * 32;
    int am = tid >> 3;
    int ak = (tid & 7) << 2;
    int bk = tid >> 4;
    int bc = (tid & 15) << 2;
    int tm = (tid >> 4) << 1;
    int tn = (tid & 15) << 2;
    float acc[2][4] = {};
    for (int kt = 0; kt < 128; kt += 32) {
        int kg = kt + ak;
        float4 raw = *(const float4*)(z1 + (size_t)(m0 + am) * 128 + kg);
        float4 g1 = *(const float4*)(gb1 + kg);
        float4 mu = *(const float4*)(bn_mean + kg);
        float4 vr = *(const float4*)(bn_var + kg);
        float4 gm = *(const float4*)(bn_gamma + kg);
        float4 bt = *(const float4*)(bn_beta + kg);
        As[ak][am]     = fmaxf(fmaf(raw.x + g1.x - mu.x, rsqrtf(vr.x + 1e-5f) * gm.x, bt.x), 0.f);
        As[ak + 1][am] = fmaxf(fmaf(raw.y + g1.y - mu.y, rsqrtf(vr.y + 1e-5f) * gm.y, bt.y), 0.f);
        As[ak + 2][am] = fmaxf(fmaf(raw.z + g1.z - mu.z, rsqrtf(vr.z + 1e-5f) * gm.z, bt.z), 0.f);
        As[ak + 3][am] = fmaxf(fmaf(raw.w + g1.w - mu.w, rsqrtf(vr.w + 1e-5f) * gm.w, bt.w), 0.f);
        #pragma unroll
        for (int j = 0; j < 2; ++j) {
            int kr = j * 16 + bk;
            *(float4*)&Bs[kr][bc] = *(const float4*)(gW2 + (size_t)(kt + kr) * 512 + n0 + bc);
        }
        __syncthreads();
        #pragma unroll
        for (int kk = 0; kk < 32; ++kk) {
            float2 a2 = *(const float2*)&As[kk][tm];
            float4 b4 = *(const float4*)&Bs[kk][tn];
            acc[0][0] = fmaf(a2.x, b4.x, acc[0][0]); acc[0][1] = fmaf(a2.x, b4.y, acc[0][1]);
            acc[0][2] = fmaf(a2.x, b4.z, acc[0][2]); acc[0][3] = fmaf(a2.x, b4.w, acc[0][3]);
            acc[1][0] = fmaf(a2.y, b4.x, acc[1][0]); acc[1][1] = fmaf(a2.y, b4.y, acc[1][1]);
            acc[1][2] = fmaf(a2.y, b4.z, acc[1][2]); acc[1][3] = fmaf(a2.y, b4.w, acc[1][3]);
        }
        __syncthreads();
    }
    float4 bb = *(const float4*)(gb2 + n0 + tn);
    #pragma unroll
    for (int i = 0; i < 2; ++i) {
        float* cp = Cout + (size_t)(m0 + tm + i) * 1024 + n0 + tn;   // Cout pre-offset by 512
        *(float4*)cp = make_float4(fmaxf(acc[i][0] + bb.x, 0.f), fmaxf(acc[i][1] + bb.y, 0.f),
                                   fmaxf(acc[i][2] + bb.z, 0.f), fmaxf(acc[i][3] + bb.w, 0.f));
    }
}

// ---------------- fusion MLP layers 1-2: split-K fp32 GEMM, atomic accumulate ----------------
#define FBM 32
#define FBN 64
#define FKS 32

__global__ __launch_bounds__(256) void k_fgemm_sk(
    const float* __restrict__ A, const float* __restrict__ B,
    float* __restrict__ C, int N, int K, int KS, int reluA)
{
    __shared__ float As[FKS][FBM + 2];   // [k][m]
    __shared__ float Bs[FKS][FBN + 4];   // [k][n]
    int tid = threadIdx.x;
    int n0 = blockIdx.x * FBN;
    int m0 = blockIdx.y * FBM;
    int kbase = blockIdx.z * KS;
    int am = tid >> 3;
    int ak = (tid & 7) << 2;
    int bk = tid >> 4;
    int bc = (tid & 15) << 2;
    int tm = (tid >> 4) << 1;
    int tn = (tid & 15) << 2;
    float acc[2][4] = {};
    for (int kt = 0; kt < KS; kt += FKS) {
        float4 a4 = *(const float4*)(A + (size_t)(m0 + am) * K + kbase + kt + ak);
        if (reluA) {
            a4.x = fmaxf(a4.x, 0.f); a4.y = fmaxf(a4.y, 0.f);
            a4.z = fmaxf(a4.z, 0.f); a4.w = fmaxf(a4.w, 0.f);
        }
        As[ak][am] = a4.x; As[ak + 1][am] = a4.y;
        As[ak + 2][am] = a4.z; As[ak + 3][am] = a4.w;
        #pragma unroll
        for (int j = 0; j < 2; ++j) {
            int kr = j * 16 + bk;
            *(float4*)&Bs[kr][bc] = *(const float4*)(B + (size_t)(kbase + kt + kr) * N + n0 + bc);
        }
        __syncthreads();
        #pragma unroll
        for (int kk = 0; kk < FKS; ++kk) {
            float2 a2 = *(const float2*)&As[kk][tm];
            float4 b4 = *(const float4*)&Bs[kk][tn];
            acc[0][0] = fmaf(a2.x, b4.x, acc[0][0]); acc[0][1] = fmaf(a2.x, b4.y, acc[0][1]);
            acc[0][2] = fmaf(a2.x, b4.z, acc[0][2]); acc[0][3] = fmaf(a2.x, b4.w, acc[0][3]);
            acc[1][0] = fmaf(a2.y, b4.x, acc[1][0]); acc[1][1] = fmaf(a2.y, b4.y, acc[1][1]);
            acc[1][2] = fmaf(a2.y, b4.z, acc[1][2]); acc[1][3] = fmaf(a2.y, b4.w, acc[1][3]);
        }
        __syncthreads();
    }
    #pragma unroll
    for (int i = 0; i < 2; ++i) {
        float* cp = C + (size_t)(m0 + tm + i) * N + n0 + tn;
        #pragma unroll
        for (int j = 0; j < 4; ++j) atomAddF(cp + j, acc[i][j]);
    }
}

// ---------------- fusion output layer (relu on load of t2) ----------------
__global__ __launch_bounds__(256) void k_fout(
    const float* __restrict__ t2, const float* __restrict__ fW3,
    const float* __restrict__ fb3, float* __restrict__ out)
{
    int lane = threadIdx.x & 63;
    int row = blockIdx.x * 4 + (threadIdx.x >> 6);
    const float* tp = t2 + (size_t)row * 128;
    float p = fmaxf(tp[lane], 0.f) * fW3[lane] + fmaxf(tp[lane + 64], 0.f) * fW3[lane + 64];
    #pragma unroll
    for (int d = 1; d < 64; d <<= 1) p += __shfl_xor(p, d);
    if (lane == 0) out[row] = p + fb3[0];
}

extern "C" void kernel_launch(void* const* d_in, const int* in_sizes, int n_in,
                              void* d_out, int out_size, void* d_ws, size_t ws_size,
                              hipStream_t stream) {
    const float* x        = (const float*)d_in[0];
    const int*   ei       = (const int*)d_in[1];
    const int*   batch    = (const int*)d_in[2];
    const float* x_gen    = (const float*)d_in[3];
    const float* W1       = (const float*)d_in[4];
    const float* att_src1 = (const float*)d_in[5];
    const float* att_dst1 = (const float*)d_in[6];
    const float* bias1    = (const float*)d_in[7];
    const float* W2       = (const float*)d_in[8];
    const float* att_src2 = (const float*)d_in[9];
    const float* att_dst2 = (const float*)d_in[10];
    const float* bias2    = (const float*)d_in[11];
    const float* gW1      = (const float*)d_in[12];
    const float* gb1      = (const float*)d_in[13];
    const float* bn_gamma = (const float*)d_in[14];
    const float* bn_beta  = (const float*)d_in[15];
    const float* bn_mean  = (const float*)d_in[16];
    const float* bn_var   = (const float*)d_in[17];
    const float* gW2      = (const float*)d_in[18];
    const float* gb2      = (const float*)d_in[19];
    const float* fW1      = (const float*)d_in[20];
    const float* fb1      = (const float*)d_in[21];
    const float* fW2      = (const float*)d_in[22];
    const float* fb2      = (const float*)d_in[23];
    const float* fW3      = (const float*)d_in[24];
    const float* fb3      = (const float*)d_in[25];
    float* out = (float*)d_out;

    const int* srcv = ei;
    const int* dstv = ei + NE;

    char* w = (char*)d_ws;
    size_t off = 0;
    auto take = [&](size_t bytes) -> void* {
        void* p = w + off;
        off += (bytes + 255) & ~(size_t)255;
        return p;
    };
    __hip_bfloat16* hbuf = (__hip_bfloat16*)take((size_t)NN * GOUTD * 2);
    __hip_bfloat16* abuf = (__hip_bfloat16*)take((size_t)NN * GOUTD * 2);
    __hip_bfloat16* xb   = (__hip_bfloat16*)take((size_t)NN * 128 * 2);   // 16 MB
    __hip_bfloat16* w1t  = (__hip_bfloat16*)take((size_t)512 * 128 * 2);
    __hip_bfloat16* w2t  = (__hip_bfloat16*)take((size_t)512 * 512 * 2);
    float* asrc   = (float*)take((size_t)NN * 8 * 4);
    float* adst   = (float*)take((size_t)NN * 8 * 4);
    int*   rowptr = (int*)take((size_t)(NN + 1) * 4);
    int*   colI   = (int*)take((size_t)NE * 4);
    int*   deg    = (int*)take((size_t)NN * 4);
    int*   fill   = (int*)take((size_t)NN * 4);
    int*   bsum   = (int*)take(256 * 4);
    int*   gstart = (int*)take((NB + 1) * 4);
    float* cbuf = (float*)xb;                       // [2048, 1024]  8 MB (aliases xb; xb dead after gemm1)
    float* z1   = cbuf + (size_t)2048 * 1024;       // [2048, 128]   1 MB (zeroed by gemm2 tail)
    float* t1   = z1 + (size_t)2048 * 128;          // [2048, 256]   2 MB
    float* t2   = t1 + (size_t)2048 * 256;          // [2048, 128]   1 MB

    // ---- conversions + prep (merged), then CSR build ----
    k_cvt_prep<<<9728, 256, 0, stream>>>(x, W1, W2, xb, w1t, w2t, deg, fill, batch, gstart);
    k_hist<<<NE / 256, 256, 0, stream>>>(dstv, deg);
    k_scan_block<<<256, 256, 0, stream>>>(deg, rowptr, bsum);
    k_scan_add2<<<256, 256, 0, stream>>>(rowptr, bsum);

    // ---- GAT layer 1 GEMM + folded CSR scatter (blocks 2048..3071) ----
    k_mfma_gemm1<<<3072, 256, 0, stream>>>(xb, w1t, hbuf, 128, att_src1, att_dst1, asrc, adst,
                                           srcv, dstv, rowptr, fill, colI);
    k_gat_agg<<<NN / 4, 256, 0, stream>>>(hbuf, asrc, adst, rowptr, colI, bias1, abuf);

    // ---- GAT layer 2 GEMM (128x256; tail inits t1/t2, zeroes z1; xb dead after gemm1) ----
    k_mfma_gemm<<<1024, 512, 0, stream>>>(abuf, w2t, hbuf, 512, att_src2, att_dst2, asrc, adst,
                                          t1, t2, fb1, fb2, z1);

    // ---- aggpool + geno1 merged (blocks [0,2048) / [2048,2560)) ----
    k_aggpool_geno1<<<NB + 512, 256, 0, stream>>>(hbuf, asrc, adst, rowptr, colI, bias2,
                                                  gstart, cbuf, x_gen, gW1, z1);

    // ---- geno layer 2 ----
    k_geno2<<<dim3(8, 64), 256, 0, stream>>>(z1, gW2, gb1, bn_mean, bn_var, bn_gamma,
                                             bn_beta, gb2, cbuf + 512);

    // ---- fusion MLP: 1024 -> 256 -> 128 -> 1 (split-K fp32, atomic accumulate) ----
    k_fgemm_sk<<<dim3(4, 64, 4), 256, 0, stream>>>(cbuf, fW1, t1, 256, 1024, 256, 0);
    k_fgemm_sk<<<dim3(2, 64, 4), 256, 0, stream>>>(t1, fW2, t2, 128, 256, 64, 1);
    k_fout<<<NB / 4, 256, 0, stream>>>(t2, fW3, fb3, out);
}